// Round 5
// baseline (156.867 us; speedup 1.0000x reference)
//
#include <hip/hip_runtime.h>
#include <hip/hip_cooperative_groups.h>

namespace cg = cooperative_groups;

#define HH 512
#define WW 512
#define NB 4
#define RR 4
#define EPSF 1e-8f

__device__ __forceinline__ float4 f4add(float4 a, float4 b) {
    return make_float4(a.x + b.x, a.y + b.y, a.z + b.z, a.w + b.w);
}
__device__ __forceinline__ float4 f4sub(float4 a, float4 b) {
    return make_float4(a.x - b.x, a.y - b.y, a.z - b.z, a.w - b.w);
}

// load 12-float horizontal window (3x aligned float4), zero-padded outside image
#define LOADW(W, P) { \
    float4 qa = vlo ? *(const float4*)((P) + gj0 - 4) : make_float4(0.f,0.f,0.f,0.f); \
    float4 qb =       *(const float4*)((P) + gj0); \
    float4 qc = vhi ? *(const float4*)((P) + gj0 + 4) : make_float4(0.f,0.f,0.f,0.f); \
    W[0]=qa.x; W[1]=qa.y; W[2]=qa.z;  W[3]=qa.w; \
    W[4]=qb.x; W[5]=qb.y; W[6]=qb.z;  W[7]=qb.w; \
    W[8]=qc.x; W[9]=qc.y; W[10]=qc.z; W[11]=qc.w; }

#define HBOXS(ch, EXPR) { \
    float p[12]; \
    _Pragma("unroll") for (int k = 0; k < 12; ++k) p[k] = (EXPR); \
    float t0 = ((p[0]+p[1])+(p[2]+p[3])) + ((p[4]+p[5])+(p[6]+p[7])) + p[8]; \
    float t1 = t0 - p[0] + p[9]; \
    float t2 = t1 - p[1] + p[10]; \
    float t3 = t2 - p[2] + p[11]; \
    *(float4*)&lds[ch][r][q4] = make_float4(t0, t1, t2, t3); }

#define SOLVE(S, I, GJ) { \
    const int i0r = (I) - RR < 0 ? 0 : (I) - RR; \
    const int i1r = (I) + RR > HH - 1 ? HH - 1 : (I) + RR; \
    const float invn = 1.0f / ((float)(i1r - i0r + 1) * wcnt); \
    float mx0 = S[0]*invn, mx1 = S[1]*invn, mx2 = S[2]*invn, my = S[3]*invn; \
    float cy0 = S[4]*invn - my*mx0; \
    float cy1 = S[5]*invn - my*mx1; \
    float cy2 = S[6]*invn - my*mx2; \
    float a00 = S[7]*invn  - mx0*mx0 + EPSF; \
    float a01 = S[8]*invn  - mx0*mx1; \
    float a02 = S[9]*invn  - mx0*mx2; \
    float a11 = S[10]*invn - mx1*mx1 + EPSF; \
    float a12 = S[11]*invn - mx1*mx2; \
    float a22 = S[12]*invn - mx2*mx2 + EPSF; \
    float c00 = a11*a22 - a12*a12; \
    float c01 = a02*a12 - a01*a22; \
    float c02 = a01*a12 - a02*a11; \
    float det = a00*c00 + a01*c01 + a02*c02; \
    float id  = 1.0f / det; \
    float i00 = c00*id, i01 = c01*id, i02 = c02*id; \
    float i11 = (a00*a22 - a02*a02)*id; \
    float i12 = (a01*a02 - a00*a12)*id; \
    float i22 = (a00*a11 - a01*a01)*id; \
    float A0 = cy0*i00 + cy1*i01 + cy2*i02; \
    float A1 = cy0*i01 + cy1*i11 + cy2*i12; \
    float A2 = cy0*i02 + cy1*i12 + cy2*i22; \
    float bb = my - (A0*mx0 + A1*mx1 + A2*mx2); \
    abp[(size_t)(I) * WW + (GJ)] = make_float4(A0, A1, A2, bb); }

// ==================== fused cooperative kernel ====================
// 1024 blocks, 4 WG/CU co-resident. Block B owns a 64x16 output tile; phase 1
// produces A,b for that exact region (two 32x16 tiles), grid-sync, phase 2
// consumes it (ab halo from same-XCD neighbors, L2-resident).
__global__ __launch_bounds__(256, 4) void k_fused(const float* __restrict__ y,
                                                  const float* __restrict__ x,
                                                  float* __restrict__ ab,
                                                  float* __restrict__ out) {
    __shared__ __align__(16) float shmem[13 * 24 * 32];   // 39,936 B
    const int B   = (int)blockIdx.x;
    const int xcd = B & 7;
    const int qq  = B >> 3;
    const int g2  = xcd * 128 + qq;       // XCD-contiguous tile id
    const int n   = g2 >> 8;
    const int rem = g2 & 255;
    const int ti  = (rem & 31) << 4;      // 16-row tile
    const int tj  = (rem >> 5) << 6;      // 64-col tile
    const int tid = (int)threadIdx.x;

    const size_t plane = (size_t)HH * WW;
    const float* yp = y + (size_t)n * plane;
    const float* xp = x + (size_t)(3 * n) * plane;
    float4* abp = (float4*)ab + (size_t)n * plane;

    // ---------------- phase 1: two 32x16 tiles -> A,b ----------------
    {
        float (*lds)[24][32] = (float (*)[24][32])shmem;
        for (int t = 0; t < 2; ++t) {
            const int tj1 = tj + (t << 5);
            if (tid < 192) {
                const int r   = tid >> 3;           // 0..23
                const int q4  = (tid & 7) << 2;     // 0..28
                const int gr  = ti - 4 + r;
                const int gj0 = tj1 + q4;
                if (gr >= 0 && gr < HH) {
                    const float* yr = yp + (size_t)gr * WW;
                    const float* ar = xp + (size_t)gr * WW;
                    const float* br = ar + plane;
                    const float* cr = br + plane;
                    const bool vlo = gj0 >= 4;
                    const bool vhi = gj0 < WW - 4;
                    float aw[12], bw[12], cw[12], yw[12];
                    LOADW(aw, ar); LOADW(bw, br); LOADW(cw, cr); LOADW(yw, yr);
                    HBOXS(0,  aw[k]);
                    HBOXS(1,  bw[k]);
                    HBOXS(2,  cw[k]);
                    HBOXS(3,  yw[k]);
                    HBOXS(4,  yw[k] * aw[k]);
                    HBOXS(5,  yw[k] * bw[k]);
                    HBOXS(6,  yw[k] * cw[k]);
                    HBOXS(7,  aw[k] * aw[k]);
                    HBOXS(8,  aw[k] * bw[k]);
                    HBOXS(9,  aw[k] * cw[k]);
                    HBOXS(10, bw[k] * bw[k]);
                    HBOXS(11, bw[k] * cw[k]);
                    HBOXS(12, cw[k] * cw[k]);
                } else {
                    const float4 z = make_float4(0.f, 0.f, 0.f, 0.f);
#pragma unroll
                    for (int ch = 0; ch < 13; ++ch) *(float4*)&lds[ch][r][q4] = z;
                }
            }
            __syncthreads();

            const int col = tid & 31;
            const int r0  = (tid >> 5) << 1;
            float s0[13], s1[13];
#pragma unroll
            for (int ch = 0; ch < 13; ++ch) {
                float v[10];
#pragma unroll
                for (int k = 0; k < 10; ++k) v[k] = lds[ch][r0 + k][col];
                float tsum = ((v[0]+v[1])+(v[2]+v[3])) + ((v[4]+v[5])+(v[6]+v[7])) + v[8];
                s0[ch] = tsum;
                s1[ch] = tsum - v[0] + v[9];
            }
            const int gj  = tj1 + col;
            const int j0r = gj - RR < 0 ? 0 : gj - RR;
            const int j1r = gj + RR > WW - 1 ? WW - 1 : gj + RR;
            const float wcnt = (float)(j1r - j0r + 1);
            SOLVE(s0, ti + r0, gj);
            SOLVE(s1, ti + r0 + 1, gj);
            __syncthreads();
        }
    }

    cg::this_grid().sync();

    // ---------------- phase 2: 64x16 tile A,b -> out ----------------
    {
        float4 (*lds2)[65] = (float4 (*)[65])shmem;   // 24 x 65 float4 = 24,960 B
        for (int task = tid; task < 24 * 16; task += 256) {
            const int r   = task >> 4;
            const int q4  = (task & 15) << 2;
            const int gr  = ti - 4 + r;
            const int gj0 = tj + q4;
            const float4 z = make_float4(0.f, 0.f, 0.f, 0.f);
            if (gr >= 0 && gr < HH) {
                const float4* rr = abp + (size_t)gr * WW;
                const bool vlo = gj0 >= 4;
                const bool vhi = gj0 < WW - 4;
                float4 wv[12];
#pragma unroll
                for (int k = 0; k < 4; ++k) wv[k]     = vlo ? rr[gj0 - 4 + k] : z;
#pragma unroll
                for (int k = 0; k < 4; ++k) wv[4 + k] = rr[gj0 + k];
#pragma unroll
                for (int k = 0; k < 4; ++k) wv[8 + k] = vhi ? rr[gj0 + 4 + k] : z;

                float4 t0 = f4add(f4add(f4add(f4add(wv[0], wv[1]), f4add(wv[2], wv[3])),
                                        f4add(f4add(wv[4], wv[5]), f4add(wv[6], wv[7]))), wv[8]);
                float4 t1 = f4add(f4sub(t0, wv[0]), wv[9]);
                float4 t2 = f4add(f4sub(t1, wv[1]), wv[10]);
                float4 t3 = f4add(f4sub(t2, wv[2]), wv[11]);
                lds2[r][q4 + 0] = t0;
                lds2[r][q4 + 1] = t1;
                lds2[r][q4 + 2] = t2;
                lds2[r][q4 + 3] = t3;
            } else {
                lds2[r][q4 + 0] = z; lds2[r][q4 + 1] = z;
                lds2[r][q4 + 2] = z; lds2[r][q4 + 3] = z;
            }
        }
        __syncthreads();

        const int run = tid & 15;
        const int row = tid >> 4;               // 0..15
        const int q4  = run << 2;

        float4 a0 = lds2[row][q4 + 0];
        float4 a1 = lds2[row][q4 + 1];
        float4 a2 = lds2[row][q4 + 2];
        float4 a3 = lds2[row][q4 + 3];
#pragma unroll
        for (int k = 1; k < 9; ++k) {
            a0 = f4add(a0, lds2[row + k][q4 + 0]);
            a1 = f4add(a1, lds2[row + k][q4 + 1]);
            a2 = f4add(a2, lds2[row + k][q4 + 2]);
            a3 = f4add(a3, lds2[row + k][q4 + 3]);
        }

        const int i   = ti + row;
        const int i0r = i - RR < 0 ? 0 : i - RR;
        const int i1r = i + RR > HH - 1 ? HH - 1 : i + RR;
        const float ic = (float)(i1r - i0r + 1);

        const int gj0 = tj + q4;
        float wc[4];
#pragma unroll
        for (int k = 0; k < 4; ++k) {
            const int jc  = gj0 + k;
            const int j0r = jc - RR < 0 ? 0 : jc - RR;
            const int j1r = jc + RR > WW - 1 ? WW - 1 : jc + RR;
            wc[k] = 1.0f / (ic * (float)(j1r - j0r + 1));
        }

        float* op = out + (size_t)n * plane;
        const size_t px = (size_t)i * WW + gj0;
        const float4 x0 = *(const float4*)(xp + px);
        const float4 x1 = *(const float4*)(xp + px + plane);
        const float4 x2 = *(const float4*)(xp + px + 2 * plane);

        float4 o;
        o.x = (a0.x * x0.x + a0.y * x1.x + a0.z * x2.x + a0.w) * wc[0];
        o.y = (a1.x * x0.y + a1.y * x1.y + a1.z * x2.y + a1.w) * wc[1];
        o.z = (a2.x * x0.z + a2.y * x1.z + a2.z * x2.z + a2.w) * wc[2];
        o.w = (a3.x * x0.w + a3.y * x1.w + a3.z * x2.w + a3.w) * wc[3];
        *(float4*)(op + px) = o;
    }
}

// ==================== fallback (R4 two-kernel path) ====================
__global__ __launch_bounds__(256, 4) void k_f1(const float* __restrict__ y,
                                               const float* __restrict__ x,
                                               float* __restrict__ ab) {
    __shared__ float lds[13][24][32];
    const int bid = (int)blockIdx.x;
    const int w   = ((bid & 7) << 8) | (bid >> 3);
    const int ti  = (w & 31) << 4;
    const int tj  = ((w >> 5) & 15) << 5;
    const int n   = w >> 9;
    const int tid = (int)threadIdx.x;

    const size_t plane = (size_t)HH * WW;
    const float* yp = y + (size_t)n * plane;
    const float* xp = x + (size_t)(3 * n) * plane;

    if (tid < 192) {
        const int r   = tid >> 3;
        const int q4  = (tid & 7) << 2;
        const int gr  = ti - 4 + r;
        const int gj0 = tj + q4;
        if (gr >= 0 && gr < HH) {
            const float* yr = yp + (size_t)gr * WW;
            const float* ar = xp + (size_t)gr * WW;
            const float* br = ar + plane;
            const float* cr = br + plane;
            const bool vlo = gj0 >= 4;
            const bool vhi = gj0 < WW - 4;
            float aw[12], bw[12], cw[12], yw[12];
            LOADW(aw, ar); LOADW(bw, br); LOADW(cw, cr); LOADW(yw, yr);
            HBOXS(0,  aw[k]);
            HBOXS(1,  bw[k]);
            HBOXS(2,  cw[k]);
            HBOXS(3,  yw[k]);
            HBOXS(4,  yw[k] * aw[k]);
            HBOXS(5,  yw[k] * bw[k]);
            HBOXS(6,  yw[k] * cw[k]);
            HBOXS(7,  aw[k] * aw[k]);
            HBOXS(8,  aw[k] * bw[k]);
            HBOXS(9,  aw[k] * cw[k]);
            HBOXS(10, bw[k] * bw[k]);
            HBOXS(11, bw[k] * cw[k]);
            HBOXS(12, cw[k] * cw[k]);
        } else {
            const float4 z = make_float4(0.f, 0.f, 0.f, 0.f);
#pragma unroll
            for (int ch = 0; ch < 13; ++ch) *(float4*)&lds[ch][r][q4] = z;
        }
    }
    __syncthreads();

    const int col = tid & 31;
    const int r0  = (tid >> 5) << 1;
    float s0[13], s1[13];
#pragma unroll
    for (int ch = 0; ch < 13; ++ch) {
        float v[10];
#pragma unroll
        for (int k = 0; k < 10; ++k) v[k] = lds[ch][r0 + k][col];
        float tsum = ((v[0]+v[1])+(v[2]+v[3])) + ((v[4]+v[5])+(v[6]+v[7])) + v[8];
        s0[ch] = tsum;
        s1[ch] = tsum - v[0] + v[9];
    }
    const int gj  = tj + col;
    const int j0r = gj - RR < 0 ? 0 : gj - RR;
    const int j1r = gj + RR > WW - 1 ? WW - 1 : gj + RR;
    const float wcnt = (float)(j1r - j0r + 1);
    float4* abp = (float4*)ab + (size_t)n * plane;
    SOLVE(s0, ti + r0, gj);
    SOLVE(s1, ti + r0 + 1, gj);
}

__global__ __launch_bounds__(256, 4) void k_f2(const float* __restrict__ ab,
                                               const float* __restrict__ x,
                                               float* __restrict__ out) {
    __shared__ float4 lds2[24][65];
    const int bid = (int)blockIdx.x;
    const int w   = ((bid & 7) << 7) | (bid >> 3);
    const int ti  = (w & 31) << 4;
    const int tj  = ((w >> 5) & 7) << 6;
    const int n   = w >> 8;
    const int tid = (int)threadIdx.x;

    const size_t plane = (size_t)HH * WW;
    const float4* abp = (const float4*)ab + (size_t)n * plane;

    for (int task = tid; task < 24 * 16; task += 256) {
        const int r   = task >> 4;
        const int q4  = (task & 15) << 2;
        const int gr  = ti - 4 + r;
        const int gj0 = tj + q4;
        const float4 z = make_float4(0.f, 0.f, 0.f, 0.f);
        if (gr >= 0 && gr < HH) {
            const float4* rr = abp + (size_t)gr * WW;
            const bool vlo = gj0 >= 4;
            const bool vhi = gj0 < WW - 4;
            float4 wv[12];
#pragma unroll
            for (int k = 0; k < 4; ++k) wv[k]     = vlo ? rr[gj0 - 4 + k] : z;
#pragma unroll
            for (int k = 0; k < 4; ++k) wv[4 + k] = rr[gj0 + k];
#pragma unroll
            for (int k = 0; k < 4; ++k) wv[8 + k] = vhi ? rr[gj0 + 4 + k] : z;

            float4 t0 = f4add(f4add(f4add(f4add(wv[0], wv[1]), f4add(wv[2], wv[3])),
                                    f4add(f4add(wv[4], wv[5]), f4add(wv[6], wv[7]))), wv[8]);
            float4 t1 = f4add(f4sub(t0, wv[0]), wv[9]);
            float4 t2 = f4add(f4sub(t1, wv[1]), wv[10]);
            float4 t3 = f4add(f4sub(t2, wv[2]), wv[11]);
            lds2[r][q4 + 0] = t0;
            lds2[r][q4 + 1] = t1;
            lds2[r][q4 + 2] = t2;
            lds2[r][q4 + 3] = t3;
        } else {
            lds2[r][q4 + 0] = z; lds2[r][q4 + 1] = z;
            lds2[r][q4 + 2] = z; lds2[r][q4 + 3] = z;
        }
    }
    __syncthreads();

    const int run = tid & 15;
    const int row = tid >> 4;
    const int q4  = run << 2;

    float4 a0 = lds2[row][q4 + 0];
    float4 a1 = lds2[row][q4 + 1];
    float4 a2 = lds2[row][q4 + 2];
    float4 a3 = lds2[row][q4 + 3];
#pragma unroll
    for (int k = 1; k < 9; ++k) {
        a0 = f4add(a0, lds2[row + k][q4 + 0]);
        a1 = f4add(a1, lds2[row + k][q4 + 1]);
        a2 = f4add(a2, lds2[row + k][q4 + 2]);
        a3 = f4add(a3, lds2[row + k][q4 + 3]);
    }

    const int i   = ti + row;
    const int i0r = i - RR < 0 ? 0 : i - RR;
    const int i1r = i + RR > HH - 1 ? HH - 1 : i + RR;
    const float ic = (float)(i1r - i0r + 1);

    const int gj0 = tj + q4;
    float wc[4];
#pragma unroll
    for (int k = 0; k < 4; ++k) {
        const int jc  = gj0 + k;
        const int j0r = jc - RR < 0 ? 0 : jc - RR;
        const int j1r = jc + RR > WW - 1 ? WW - 1 : jc + RR;
        wc[k] = 1.0f / (ic * (float)(j1r - j0r + 1));
    }

    const float* xp = x + (size_t)(3 * n) * plane;
    float* op = out + (size_t)n * plane;
    const size_t px = (size_t)i * WW + gj0;

    const float4 x0 = *(const float4*)(xp + px);
    const float4 x1 = *(const float4*)(xp + px + plane);
    const float4 x2 = *(const float4*)(xp + px + 2 * plane);

    float4 o;
    o.x = (a0.x * x0.x + a0.y * x1.x + a0.z * x2.x + a0.w) * wc[0];
    o.y = (a1.x * x0.y + a1.y * x1.y + a1.z * x2.y + a1.w) * wc[1];
    o.z = (a2.x * x0.z + a2.y * x1.z + a2.z * x2.z + a2.w) * wc[2];
    o.w = (a3.x * x0.w + a3.y * x1.w + a3.z * x2.w + a3.w) * wc[3];
    *(float4*)(op + px) = o;
}

extern "C" void kernel_launch(void* const* d_in, const int* in_sizes, int n_in,
                              void* d_out, int out_size, void* d_ws, size_t ws_size,
                              hipStream_t stream) {
    const float* y = (const float*)d_in[0];   // (4,1,512,512)
    const float* x = (const float*)d_in[1];   // (4,3,512,512)
    float* out = (float*)d_out;               // (4,1,512,512)
    float* ab  = (float*)d_ws;                // (4,512,512,4) interleaved A,b = 16 MB

    void* args[] = { (void*)&y, (void*)&x, (void*)&ab, (void*)&out };
    hipError_t rc = hipLaunchCooperativeKernel((const void*)k_fused,
                                               dim3(1024), dim3(256),
                                               args, 0u, stream);
    if (rc != hipSuccess) {
        // cooperative launch unavailable (e.g. under capture): two-kernel path
        k_f1<<<dim3(2048), dim3(256), 0, stream>>>(y, x, ab);
        k_f2<<<dim3(1024), dim3(256), 0, stream>>>(ab, x, out);
    }
}

// Round 6
// 42.204 us; speedup vs baseline: 3.7168x; 3.7168x over previous
//
#include <hip/hip_runtime.h>

#define HH 512
#define WW 512
#define NB 4
#define RR 4
#define EPSF 1e-8f

__device__ __forceinline__ float4 f4add(float4 a, float4 b) {
    return make_float4(a.x + b.x, a.y + b.y, a.z + b.z, a.w + b.w);
}
__device__ __forceinline__ float4 f4sub(float4 a, float4 b) {
    return make_float4(a.x - b.x, a.y - b.y, a.z - b.z, a.w - b.w);
}

// load 12-float horizontal window (3x aligned float4), zero-padded outside image
#define LOADW(W, P) { \
    float4 qa = vlo ? *(const float4*)((P) + gj0 - 4) : make_float4(0.f,0.f,0.f,0.f); \
    float4 qb =       *(const float4*)((P) + gj0); \
    float4 qc = vhi ? *(const float4*)((P) + gj0 + 4) : make_float4(0.f,0.f,0.f,0.f); \
    W[0]=qa.x; W[1]=qa.y; W[2]=qa.z;  W[3]=qa.w; \
    W[4]=qb.x; W[5]=qb.y; W[6]=qb.z;  W[7]=qb.w; \
    W[8]=qc.x; W[9]=qc.y; W[10]=qc.z; W[11]=qc.w; }

// horizontal 9-box of 4 consecutive cols via sliding sums into hs[ch][0..3]
#define HBOX(ch, EXPR) { \
    float p[12]; \
    _Pragma("unroll") for (int k = 0; k < 12; ++k) p[k] = (EXPR); \
    hs[ch][0] = ((p[0]+p[1])+(p[2]+p[3])) + ((p[4]+p[5])+(p[6]+p[7])) + p[8]; \
    hs[ch][1] = hs[ch][0] - p[0] + p[9]; \
    hs[ch][2] = hs[ch][1] - p[1] + p[10]; \
    hs[ch][3] = hs[ch][2] - p[2] + p[11]; }

// 3x3 symmetric solve from grouped sums; writes interleaved A,b
#define SOLVEG(sA, sB, sC, sDv, I, GJ) { \
    const int i0r = (I) - RR < 0 ? 0 : (I) - RR; \
    const int i1r = (I) + RR > HH - 1 ? HH - 1 : (I) + RR; \
    const float invn = 1.0f / ((float)(i1r - i0r + 1) * wcnt); \
    float mx0 = sA.x*invn, mx1 = sA.y*invn, mx2 = sA.z*invn, my = sA.w*invn; \
    float cy0 = sB.x*invn - my*mx0; \
    float cy1 = sB.y*invn - my*mx1; \
    float cy2 = sB.z*invn - my*mx2; \
    float a00 = sB.w*invn - mx0*mx0 + EPSF; \
    float a01 = sC.x*invn - mx0*mx1; \
    float a02 = sC.y*invn - mx0*mx2; \
    float a11 = sC.z*invn - mx1*mx1 + EPSF; \
    float a12 = sC.w*invn - mx1*mx2; \
    float a22 = (sDv)*invn - mx2*mx2 + EPSF; \
    float c00 = a11*a22 - a12*a12; \
    float c01 = a02*a12 - a01*a22; \
    float c02 = a01*a12 - a02*a11; \
    float det = a00*c00 + a01*c01 + a02*c02; \
    float id  = 1.0f / det; \
    float i00 = c00*id, i01 = c01*id, i02 = c02*id; \
    float i11 = (a00*a22 - a02*a02)*id; \
    float i12 = (a01*a02 - a00*a12)*id; \
    float i22 = (a00*a11 - a01*a01)*id; \
    float A0 = cy0*i00 + cy1*i01 + cy2*i02; \
    float A1 = cy0*i01 + cy1*i11 + cy2*i12; \
    float A2 = cy0*i02 + cy1*i12 + cy2*i22; \
    float bb = my - (A0*mx0 + A1*mx1 + A2*mx2); \
    abp[(size_t)(I) * WW + (GJ)] = make_float4(A0, A1, A2, bb); }

// ============ Kernel F1: y,x -> A,b (32x16 tile; channel-grouped LDS) ============
__global__ __launch_bounds__(256, 4) void k_f1(const float* __restrict__ y,
                                               const float* __restrict__ x,
                                               float* __restrict__ ab) {
    // grouped h-sums: A={sx0,sx1,sx2,sy} B={syx0,syx1,syx2,sxx00} C={sxx01,sxx02,sxx11,sxx12} D=sxx22
    __shared__ float4 ldsA[24][32];
    __shared__ float4 ldsB[24][32];
    __shared__ float4 ldsC[24][32];
    __shared__ float  ldsD[24][32];        // total 39,936 B -> 4 WG/CU
    const int bid = (int)blockIdx.x;
    const int w   = ((bid & 7) << 8) | (bid >> 3);   // XCD slab
    const int ti  = (w & 31) << 4;
    const int tj  = ((w >> 5) & 15) << 5;
    const int n   = w >> 9;
    const int tid = (int)threadIdx.x;

    const size_t plane = (size_t)HH * WW;
    const float* yp = y + (size_t)n * plane;
    const float* xp = x + (size_t)(3 * n) * plane;

    // ---- stage 1: h-sums for 24 rows x 32 cols (192 threads, 4 cols each) ----
    if (tid < 192) {
        const int r   = tid >> 3;            // 0..23
        const int q4  = (tid & 7) << 2;      // 0,4,..,28
        const int gr  = ti - 4 + r;
        const int gj0 = tj + q4;
        if (gr >= 0 && gr < HH) {
            const float* yr = yp + (size_t)gr * WW;
            const float* ar = xp + (size_t)gr * WW;
            const float* br = ar + plane;
            const float* cr = br + plane;
            const bool vlo = gj0 >= 4;
            const bool vhi = gj0 < WW - 4;
            float aw[12], bw[12], cw[12], yw[12];
            LOADW(aw, ar); LOADW(bw, br); LOADW(cw, cr); LOADW(yw, yr);
            float hs[13][4];
            HBOX(0,  aw[k]);
            HBOX(1,  bw[k]);
            HBOX(2,  cw[k]);
            HBOX(3,  yw[k]);
            HBOX(4,  yw[k] * aw[k]);
            HBOX(5,  yw[k] * bw[k]);
            HBOX(6,  yw[k] * cw[k]);
            HBOX(7,  aw[k] * aw[k]);
            HBOX(8,  aw[k] * bw[k]);
            HBOX(9,  aw[k] * cw[k]);
            HBOX(10, bw[k] * bw[k]);
            HBOX(11, bw[k] * cw[k]);
            HBOX(12, cw[k] * cw[k]);
#pragma unroll
            for (int c = 0; c < 4; ++c) {
                ldsA[r][q4 + c] = make_float4(hs[0][c], hs[1][c], hs[2][c],  hs[3][c]);
                ldsB[r][q4 + c] = make_float4(hs[4][c], hs[5][c], hs[6][c],  hs[7][c]);
                ldsC[r][q4 + c] = make_float4(hs[8][c], hs[9][c], hs[10][c], hs[11][c]);
                ldsD[r][q4 + c] = hs[12][c];
            }
        } else {
            const float4 z = make_float4(0.f, 0.f, 0.f, 0.f);
#pragma unroll
            for (int c = 0; c < 4; ++c) {
                ldsA[r][q4 + c] = z; ldsB[r][q4 + c] = z;
                ldsC[r][q4 + c] = z; ldsD[r][q4 + c] = 0.f;
            }
        }
    }
    __syncthreads();

    // ---- stage 2: vertical 9-sum (sliding pair) + solve, 2 rows/thread ----
    const int col = tid & 31;
    const int r0  = (tid >> 5) << 1;         // 0,2,..,14

    float4 rA0 = ldsA[r0][col], rB0 = ldsB[r0][col], rC0 = ldsC[r0][col];
    float  rD0 = ldsD[r0][col];
    float4 sA = rA0, sB = rB0, sC = rC0;
    float  sD = rD0;
#pragma unroll
    for (int k = 1; k < 9; ++k) {
        sA = f4add(sA, ldsA[r0 + k][col]);
        sB = f4add(sB, ldsB[r0 + k][col]);
        sC = f4add(sC, ldsC[r0 + k][col]);
        sD += ldsD[r0 + k][col];
    }
    float4 sA1 = f4add(f4sub(sA, rA0), ldsA[r0 + 9][col]);
    float4 sB1 = f4add(f4sub(sB, rB0), ldsB[r0 + 9][col]);
    float4 sC1 = f4add(f4sub(sC, rC0), ldsC[r0 + 9][col]);
    float  sD1 = sD - rD0 + ldsD[r0 + 9][col];

    const int gj  = tj + col;
    const int j0r = gj - RR < 0 ? 0 : gj - RR;
    const int j1r = gj + RR > WW - 1 ? WW - 1 : gj + RR;
    const float wcnt = (float)(j1r - j0r + 1);
    float4* abp = (float4*)ab + (size_t)n * plane;

    SOLVEG(sA,  sB,  sC,  sD,  ti + r0,     gj);
    SOLVEG(sA1, sB1, sC1, sD1, ti + r0 + 1, gj);
}

// ============ Kernel F2: A,b,x -> out (64x32 tile) ============
__global__ __launch_bounds__(256, 4) void k_f2(const float* __restrict__ ab,
                                               const float* __restrict__ x,
                                               float* __restrict__ out) {
    __shared__ float4 lds2[40][64];          // 40,960 B -> 4 WG/CU (exactly 160 KB)
    const int bid = (int)blockIdx.x;         // 0..511
    const int w   = ((bid & 7) << 6) | (bid >> 3);
    const int rem = w & 127;
    const int ti  = (rem & 15) << 5;         // 32-row tile
    const int tj  = (rem >> 4) << 6;         // 64-col tile
    const int n   = w >> 7;
    const int tid = (int)threadIdx.x;

    const size_t plane = (size_t)HH * WW;
    const float4* abp = (const float4*)ab + (size_t)n * plane;

    // ---- stage 1: h-box of interleaved A,b into LDS (40 rows x 64 cols) ----
    for (int task = tid; task < 40 * 16; task += 256) {
        const int r   = task >> 4;           // 0..39
        const int q4  = (task & 15) << 2;
        const int gr  = ti - 4 + r;
        const int gj0 = tj + q4;
        const float4 z = make_float4(0.f, 0.f, 0.f, 0.f);
        if (gr >= 0 && gr < HH) {
            const float4* rr = abp + (size_t)gr * WW;
            const bool vlo = gj0 >= 4;
            const bool vhi = gj0 < WW - 4;
            float4 wv[12];
#pragma unroll
            for (int k = 0; k < 4; ++k) wv[k]     = vlo ? rr[gj0 - 4 + k] : z;
#pragma unroll
            for (int k = 0; k < 4; ++k) wv[4 + k] = rr[gj0 + k];
#pragma unroll
            for (int k = 0; k < 4; ++k) wv[8 + k] = vhi ? rr[gj0 + 4 + k] : z;

            float4 t0 = f4add(f4add(f4add(f4add(wv[0], wv[1]), f4add(wv[2], wv[3])),
                                    f4add(f4add(wv[4], wv[5]), f4add(wv[6], wv[7]))), wv[8]);
            float4 t1 = f4add(f4sub(t0, wv[0]), wv[9]);
            float4 t2 = f4add(f4sub(t1, wv[1]), wv[10]);
            float4 t3 = f4add(f4sub(t2, wv[2]), wv[11]);
            lds2[r][q4 + 0] = t0;
            lds2[r][q4 + 1] = t1;
            lds2[r][q4 + 2] = t2;
            lds2[r][q4 + 3] = t3;
        } else {
            lds2[r][q4 + 0] = z; lds2[r][q4 + 1] = z;
            lds2[r][q4 + 2] = z; lds2[r][q4 + 3] = z;
        }
    }
    __syncthreads();

    // ---- stage 2: vertical 9-sum (sliding pair) + combine, 2 rows x 4 cols/thread ----
    const int run  = tid & 15;
    const int row2 = (tid >> 4) << 1;        // 0,2,..,30
    const int q4   = run << 2;
    const int gj0  = tj + q4;

    float jin[4];
#pragma unroll
    for (int c = 0; c < 4; ++c) {
        const int jc  = gj0 + c;
        const int j0r = jc - RR < 0 ? 0 : jc - RR;
        const int j1r = jc + RR > WW - 1 ? WW - 1 : jc + RR;
        jin[c] = (float)(j1r - j0r + 1);
    }

    float4 r0c[4], s[4];
#pragma unroll
    for (int c = 0; c < 4; ++c) { r0c[c] = lds2[row2][q4 + c]; s[c] = r0c[c]; }
#pragma unroll
    for (int k = 1; k < 9; ++k)
#pragma unroll
        for (int c = 0; c < 4; ++c) s[c] = f4add(s[c], lds2[row2 + k][q4 + c]);

    const float* xp = x + (size_t)(3 * n) * plane;
    float* op = out + (size_t)n * plane;

#pragma unroll
    for (int rr = 0; rr < 2; ++rr) {
        const int i   = ti + row2 + rr;
        const int i0r = i - RR < 0 ? 0 : i - RR;
        const int i1r = i + RR > HH - 1 ? HH - 1 : i + RR;
        const float ic = (float)(i1r - i0r + 1);

        const size_t px = (size_t)i * WW + gj0;
        const float4 x0 = *(const float4*)(xp + px);
        const float4 x1 = *(const float4*)(xp + px + plane);
        const float4 x2 = *(const float4*)(xp + px + 2 * plane);

        float4 o;
        o.x = (s[0].x * x0.x + s[0].y * x1.x + s[0].z * x2.x + s[0].w) / (ic * jin[0]);
        o.y = (s[1].x * x0.y + s[1].y * x1.y + s[1].z * x2.y + s[1].w) / (ic * jin[1]);
        o.z = (s[2].x * x0.z + s[2].y * x1.z + s[2].z * x2.z + s[2].w) / (ic * jin[2]);
        o.w = (s[3].x * x0.w + s[3].y * x1.w + s[3].z * x2.w + s[3].w) / (ic * jin[3]);
        *(float4*)(op + px) = o;

        if (rr == 0) {
#pragma unroll
            for (int c = 0; c < 4; ++c)
                s[c] = f4add(f4sub(s[c], r0c[c]), lds2[row2 + 9][q4 + c]);
        }
    }
}

extern "C" void kernel_launch(void* const* d_in, const int* in_sizes, int n_in,
                              void* d_out, int out_size, void* d_ws, size_t ws_size,
                              hipStream_t stream) {
    const float* y = (const float*)d_in[0];   // (4,1,512,512)
    const float* x = (const float*)d_in[1];   // (4,3,512,512)
    float* out = (float*)d_out;               // (4,1,512,512)
    float* ab  = (float*)d_ws;                // (4,512,512,4) interleaved A,b = 16 MB

    k_f1<<<dim3(2048), dim3(256), 0, stream>>>(y, x, ab);
    k_f2<<<dim3(512),  dim3(256), 0, stream>>>(ab, x, out);
}

// Round 7
// 41.951 us; speedup vs baseline: 3.7392x; 1.0060x over previous
//
#include <hip/hip_runtime.h>

#define HH 512
#define WW 512
#define NB 4
#define RR 4
#define EPSF 1e-8f

__device__ __forceinline__ float4 f4add(float4 a, float4 b) {
    return make_float4(a.x + b.x, a.y + b.y, a.z + b.z, a.w + b.w);
}
__device__ __forceinline__ float4 f4sub(float4 a, float4 b) {
    return make_float4(a.x - b.x, a.y - b.y, a.z - b.z, a.w - b.w);
}

// safe aligned float4 load: clamps address into the row, zeroes invalid lanes
__device__ __forceinline__ float4 ld4s(const float* p, int off, bool v) {
    const float4 r = *(const float4*)(p + (v ? off : 0));
    return v ? r : make_float4(0.f, 0.f, 0.f, 0.f);
}

// horizontal 9-box of 4 consecutive cols via sliding sums into hs[ch][0..3]
#define HBOX(ch, EXPR) { \
    float p[12]; \
    _Pragma("unroll") for (int k = 0; k < 12; ++k) p[k] = (EXPR); \
    hs[ch][0] = ((p[0]+p[1])+(p[2]+p[3])) + ((p[4]+p[5])+(p[6]+p[7])) + p[8]; \
    hs[ch][1] = hs[ch][0] - p[0] + p[9]; \
    hs[ch][2] = hs[ch][1] - p[1] + p[10]; \
    hs[ch][3] = hs[ch][2] - p[2] + p[11]; }

// 3x3 symmetric solve from grouped box sums -> (A0,A1,A2,b)
__device__ __forceinline__ float4 solve_px(float4 sA, float4 sB, float4 sC, float sD,
                                           float invn) {
    float mx0 = sA.x*invn, mx1 = sA.y*invn, mx2 = sA.z*invn, my = sA.w*invn;
    float cy0 = sB.x*invn - my*mx0;
    float cy1 = sB.y*invn - my*mx1;
    float cy2 = sB.z*invn - my*mx2;
    float a00 = sB.w*invn - mx0*mx0 + EPSF;
    float a01 = sC.x*invn - mx0*mx1;
    float a02 = sC.y*invn - mx0*mx2;
    float a11 = sC.z*invn - mx1*mx1 + EPSF;
    float a12 = sC.w*invn - mx1*mx2;
    float a22 = sD  *invn - mx2*mx2 + EPSF;
    float c00 = a11*a22 - a12*a12;
    float c01 = a02*a12 - a01*a22;
    float c02 = a01*a12 - a02*a11;
    float det = a00*c00 + a01*c01 + a02*c02;
    float id  = 1.0f / det;
    float i00 = c00*id, i01 = c01*id, i02 = c02*id;
    float i11 = (a00*a22 - a02*a02)*id;
    float i12 = (a01*a02 - a00*a12)*id;
    float i22 = (a00*a11 - a01*a01)*id;
    float A0 = cy0*i00 + cy1*i01 + cy2*i02;
    float A1 = cy0*i01 + cy1*i11 + cy2*i12;
    float A2 = cy0*i02 + cy1*i12 + cy2*i22;
    float bb = my - (A0*mx0 + A1*mx1 + A2*mx2);
    return make_float4(A0, A1, A2, bb);
}

// ============ Kernel G1: y,x -> Ah (h-box-summed A,b), 32x16 out tile ============
// stage 1: 13-channel product h-sums, 24 rows x 40 h-cols (grouped float4 LDS)
// stage 2a: vertical 9-sum + solve on 40 cols x 16 rows -> A,b in LDS
// stage 2b: horizontal 9-SUM of A,b -> Ah global (32 cols x 16 rows)
__global__ __launch_bounds__(256, 2) void k_g1(const float* __restrict__ y,
                                               const float* __restrict__ x,
                                               float* __restrict__ Ah) {
    __shared__ float4 ldsA[24][40];
    __shared__ float4 ldsB[24][40];
    __shared__ float4 ldsC[24][40];
    __shared__ float  ldsD[24][40];
    __shared__ float4 ldsAB[16][40];        // total 60,160 B -> 2 WG/CU

    const int bid = (int)blockIdx.x;        // 2048
    const int w   = ((bid & 7) << 8) | (bid >> 3);   // XCD slab: XCD owns (n=x/2, col-half=x&1)
    const int ti  = (w & 31) << 4;          // row tile (fastest: vertical L2 locality)
    const int tj  = ((w >> 5) & 15) << 5;   // col tile
    const int n   = w >> 9;
    const int tid = (int)threadIdx.x;

    const size_t plane = (size_t)HH * WW;
    const float* yp = y + (size_t)n * plane;
    const float* xp = x + (size_t)(3 * n) * plane;

    // ---- stage 1: h-sums for 24 rows x 40 h-cols (240 tasks, 4 cols each) ----
    if (tid < 240) {
        const int r   = tid / 10;            // 0..23
        const int q   = tid % 10;            // 0..9
        const int gr  = ti - 4 + r;
        const int gj0 = tj - 4 + (q << 2);   // h-col base (global), multiple of 4
        if (gr >= 0 && gr < HH) {
            const bool v0 = (unsigned)(gj0 - 4) <= (unsigned)(WW - 4);
            const bool v1 = (unsigned)(gj0)     <= (unsigned)(WW - 4);
            const bool v2 = (unsigned)(gj0 + 4) <= (unsigned)(WW - 4);
            const float* yr = yp + (size_t)gr * WW;
            const float* ar = xp + (size_t)gr * WW;
            const float* br = ar + plane;
            const float* cr = br + plane;
#define LOADW(Wv, P) { \
            float4 qa = ld4s((P), gj0 - 4, v0); \
            float4 qb = ld4s((P), gj0,     v1); \
            float4 qc = ld4s((P), gj0 + 4, v2); \
            Wv[0]=qa.x; Wv[1]=qa.y; Wv[2]=qa.z;  Wv[3]=qa.w; \
            Wv[4]=qb.x; Wv[5]=qb.y; Wv[6]=qb.z;  Wv[7]=qb.w; \
            Wv[8]=qc.x; Wv[9]=qc.y; Wv[10]=qc.z; Wv[11]=qc.w; }
            float aw[12], bw[12], cw[12], yw[12];
            LOADW(aw, ar); LOADW(bw, br); LOADW(cw, cr); LOADW(yw, yr);
#undef LOADW
            float hs[13][4];
            HBOX(0,  aw[k]);
            HBOX(1,  bw[k]);
            HBOX(2,  cw[k]);
            HBOX(3,  yw[k]);
            HBOX(4,  yw[k] * aw[k]);
            HBOX(5,  yw[k] * bw[k]);
            HBOX(6,  yw[k] * cw[k]);
            HBOX(7,  aw[k] * aw[k]);
            HBOX(8,  aw[k] * bw[k]);
            HBOX(9,  aw[k] * cw[k]);
            HBOX(10, bw[k] * bw[k]);
            HBOX(11, bw[k] * cw[k]);
            HBOX(12, cw[k] * cw[k]);
            const int hc = q << 2;
#pragma unroll
            for (int c = 0; c < 4; ++c) {
                ldsA[r][hc + c] = make_float4(hs[0][c], hs[1][c], hs[2][c],  hs[3][c]);
                ldsB[r][hc + c] = make_float4(hs[4][c], hs[5][c], hs[6][c],  hs[7][c]);
                ldsC[r][hc + c] = make_float4(hs[8][c], hs[9][c], hs[10][c], hs[11][c]);
                ldsD[r][hc + c] = hs[12][c];
            }
        } else {
            const float4 z = make_float4(0.f, 0.f, 0.f, 0.f);
            const int hc = q << 2;
#pragma unroll
            for (int c = 0; c < 4; ++c) {
                ldsA[r][hc + c] = z; ldsB[r][hc + c] = z;
                ldsC[r][hc + c] = z; ldsD[r][hc + c] = 0.f;
            }
        }
    }
    __syncthreads();

    // ---- stage 2a: vertical 9-sum (sliding pair) + solve -> ldsAB (40 x 16) ----
    for (int t = tid; t < 320; t += 256) {
        const int c  = t % 40;
        const int rp = t / 40;               // 0..7
        const int r0 = rp << 1;

        float4 fA = ldsA[r0][c], fB = ldsB[r0][c], fC = ldsC[r0][c];
        float  fD = ldsD[r0][c];
        float4 sA = fA, sB = fB, sC = fC;
        float  sD = fD;
#pragma unroll
        for (int k = 1; k < 9; ++k) {
            sA = f4add(sA, ldsA[r0 + k][c]);
            sB = f4add(sB, ldsB[r0 + k][c]);
            sC = f4add(sC, ldsC[r0 + k][c]);
            sD += ldsD[r0 + k][c];
        }

        const int gj = tj - 4 + c;
        const bool cv = (unsigned)gj < (unsigned)WW;
        const int j0r = gj - RR < 0 ? 0 : gj - RR;
        const int j1r = gj + RR > WW - 1 ? WW - 1 : gj + RR;
        const float wcnt = (float)(j1r - j0r + 1);
        const float4 z = make_float4(0.f, 0.f, 0.f, 0.f);

        {
            const int I   = ti + r0;
            const int i0r = I - RR < 0 ? 0 : I - RR;
            const int i1r = I + RR > HH - 1 ? HH - 1 : I + RR;
            const float invn = 1.0f / ((float)(i1r - i0r + 1) * wcnt);
            float4 abv = solve_px(sA, sB, sC, sD, invn);
            ldsAB[r0][c] = cv ? abv : z;
        }
        sA = f4add(f4sub(sA, fA), ldsA[r0 + 9][c]);
        sB = f4add(f4sub(sB, fB), ldsB[r0 + 9][c]);
        sC = f4add(f4sub(sC, fC), ldsC[r0 + 9][c]);
        sD = sD - fD + ldsD[r0 + 9][c];
        {
            const int I   = ti + r0 + 1;
            const int i0r = I - RR < 0 ? 0 : I - RR;
            const int i1r = I + RR > HH - 1 ? HH - 1 : I + RR;
            const float invn = 1.0f / ((float)(i1r - i0r + 1) * wcnt);
            float4 abv = solve_px(sA, sB, sC, sD, invn);
            ldsAB[r0 + 1][c] = cv ? abv : z;
        }
    }
    __syncthreads();

    // ---- stage 2b: horizontal 9-SUM of A,b -> Ah (32 cols x 16 rows) ----
    if (tid < 128) {
        const int r  = tid >> 3;             // 0..15
        const int q  = tid & 7;              // 0..7
        const int lc = q << 2;               // out col local base
        float4 wv[12];
#pragma unroll
        for (int k = 0; k < 12; ++k) wv[k] = ldsAB[r][lc + k];
        float4 t0 = f4add(f4add(f4add(f4add(wv[0], wv[1]), f4add(wv[2], wv[3])),
                                f4add(f4add(wv[4], wv[5]), f4add(wv[6], wv[7]))), wv[8]);
        float4 t1 = f4add(f4sub(t0, wv[0]), wv[9]);
        float4 t2 = f4add(f4sub(t1, wv[1]), wv[10]);
        float4 t3 = f4add(f4sub(t2, wv[2]), wv[11]);
        float4* dst = (float4*)Ah + (size_t)n * plane + (size_t)(ti + r) * WW + tj + lc;
        dst[0] = t0; dst[1] = t1; dst[2] = t2; dst[3] = t3;
    }
}

// ============ Kernel G2: streaming vertical 9-box of Ah + /N + combine ============
// no LDS, no barrier; 4 rows/thread sliding window; Ah reads are same-XCD L2 hits
__global__ __launch_bounds__(256, 4) void k_g2(const float* __restrict__ Ah,
                                               const float* __restrict__ x,
                                               float* __restrict__ out) {
    const int bid  = (int)blockIdx.x;       // 1024
    const int w2   = ((bid & 7) << 7) | (bid >> 3);   // matches k_g1's XCD map
    const int n    = w2 >> 8;
    const int half = (w2 >> 7) & 1;
    const int rg   = w2 & 127;              // row-group: rows 4rg..4rg+3
    const int col  = (half << 8) | (int)threadIdx.x;
    const int ib   = rg << 2;

    const size_t plane = (size_t)HH * WW;
    const float4* ahp = (const float4*)Ah + (size_t)n * plane;

    float4 s0 = make_float4(0.f,0.f,0.f,0.f), s1 = s0, s2 = s0, s3 = s0;
#pragma unroll
    for (int r = 0; r < 12; ++r) {
        const int row = ib - 4 + r;
        if (row >= 0 && row < HH) {          // wave-uniform
            const float4 h = ahp[(size_t)row * WW + col];
            if (r <= 8)            s0 = f4add(s0, h);
            if (r >= 1 && r <= 9)  s1 = f4add(s1, h);
            if (r >= 2 && r <= 10) s2 = f4add(s2, h);
            if (r >= 3)            s3 = f4add(s3, h);
        }
    }

    const int j0r = col - RR < 0 ? 0 : col - RR;
    const int j1r = col + RR > WW - 1 ? WW - 1 : col + RR;
    const float jcnt = (float)(j1r - j0r + 1);

    const float* xp = x + (size_t)(3 * n) * plane;
    float* op = out + (size_t)n * plane;

#define FIN(S, K) { \
    const int i   = ib + (K); \
    const int i0r = i - RR < 0 ? 0 : i - RR; \
    const int i1r = i + RR > HH - 1 ? HH - 1 : i + RR; \
    const float invn = 1.0f / ((float)(i1r - i0r + 1) * jcnt); \
    const size_t px = (size_t)i * WW + col; \
    const float x0 = xp[px]; \
    const float x1 = xp[px + plane]; \
    const float x2 = xp[px + 2 * plane]; \
    op[px] = (S.x * x0 + S.y * x1 + S.z * x2 + S.w) * invn; }

    FIN(s0, 0);
    FIN(s1, 1);
    FIN(s2, 2);
    FIN(s3, 3);
#undef FIN
}

extern "C" void kernel_launch(void* const* d_in, const int* in_sizes, int n_in,
                              void* d_out, int out_size, void* d_ws, size_t ws_size,
                              hipStream_t stream) {
    const float* y = (const float*)d_in[0];   // (4,1,512,512)
    const float* x = (const float*)d_in[1];   // (4,3,512,512)
    float* out = (float*)d_out;               // (4,1,512,512)
    float* Ah  = (float*)d_ws;                // (4,512,512,4) h-summed A,b = 16 MB

    k_g1<<<dim3(2048), dim3(256), 0, stream>>>(y, x, Ah);
    k_g2<<<dim3(1024), dim3(256), 0, stream>>>(Ah, x, out);
}

// Round 8
// 40.682 us; speedup vs baseline: 3.8559x; 1.0312x over previous
//
#include <hip/hip_runtime.h>

#define HH 512
#define WW 512
#define NB 4
#define RR 4
#define EPSF 1e-8f

// LDS layout (bytes), total 81,920 -> exactly 2 WG/CU (160 KiB):
//   [0,      61440): prodA/B/C  float4[32][40] each (20,480 B apiece)   stages 1-2a
//   [61440,  66560): prodD      float [32][40]                          stages 1-2a
//   [66560,  81920): AB         float4[24][40]                          stages 2a-2b
//   [0,      12288): Ahs        float4[24][32]  (aliases prodA)         stages 2b-3
#define PROD_F4   1280   // 32*40
#define SMEM_BYTES 81920

__device__ __forceinline__ float4 f4add(float4 a, float4 b) {
    return make_float4(a.x + b.x, a.y + b.y, a.z + b.z, a.w + b.w);
}
__device__ __forceinline__ float4 f4sub(float4 a, float4 b) {
    return make_float4(a.x - b.x, a.y - b.y, a.z - b.z, a.w - b.w);
}
__device__ __forceinline__ float4 ld4s(const float* p, int off, bool v) {
    const float4 r = *(const float4*)(p + (v ? off : 0));
    return v ? r : make_float4(0.f, 0.f, 0.f, 0.f);
}

// horizontal 9-box of 4 consecutive cols via sliding sums into hs[ch][0..3]
#define HBOX(ch, EXPR) { \
    float p[12]; \
    _Pragma("unroll") for (int k = 0; k < 12; ++k) p[k] = (EXPR); \
    hs[ch][0] = ((p[0]+p[1])+(p[2]+p[3])) + ((p[4]+p[5])+(p[6]+p[7])) + p[8]; \
    hs[ch][1] = hs[ch][0] - p[0] + p[9]; \
    hs[ch][2] = hs[ch][1] - p[1] + p[10]; \
    hs[ch][3] = hs[ch][2] - p[2] + p[11]; }

// 3x3 symmetric solve from grouped box sums -> (A0,A1,A2,b)
__device__ __forceinline__ float4 solve_px(float4 sA, float4 sB, float4 sC, float sD,
                                           float invn) {
    float mx0 = sA.x*invn, mx1 = sA.y*invn, mx2 = sA.z*invn, my = sA.w*invn;
    float cy0 = sB.x*invn - my*mx0;
    float cy1 = sB.y*invn - my*mx1;
    float cy2 = sB.z*invn - my*mx2;
    float a00 = sB.w*invn - mx0*mx0 + EPSF;
    float a01 = sC.x*invn - mx0*mx1;
    float a02 = sC.y*invn - mx0*mx2;
    float a11 = sC.z*invn - mx1*mx1 + EPSF;
    float a12 = sC.w*invn - mx1*mx2;
    float a22 = sD  *invn - mx2*mx2 + EPSF;
    float c00 = a11*a22 - a12*a12;
    float c01 = a02*a12 - a01*a22;
    float c02 = a01*a12 - a02*a11;
    float det = a00*c00 + a01*c01 + a02*c02;
    float id  = 1.0f / det;
    float i00 = c00*id, i01 = c01*id, i02 = c02*id;
    float i11 = (a00*a22 - a02*a02)*id;
    float i12 = (a01*a02 - a00*a12)*id;
    float i22 = (a00*a11 - a01*a01)*id;
    float A0 = cy0*i00 + cy1*i01 + cy2*i02;
    float A1 = cy0*i01 + cy1*i11 + cy2*i12;
    float A2 = cy0*i02 + cy1*i12 + cy2*i22;
    float bb = my - (A0*mx0 + A1*mx1 + A2*mx2);
    return make_float4(A0, A1, A2, bb);
}

// ==================== fully-fused kernel: y,x -> out ====================
// Block owns a 32x16 output tile. All intermediates stay in LDS; halo A,b
// solves are recomputed redundantly (1.875x) instead of exchanged.
__global__ __launch_bounds__(256, 2) void k_all(const float* __restrict__ y,
                                                const float* __restrict__ x,
                                                float* __restrict__ out) {
    __shared__ __align__(16) char smem[SMEM_BYTES];
    float4* prodA = (float4*)smem;                    // [32][40]
    float4* prodB = prodA + PROD_F4;
    float4* prodC = prodB + PROD_F4;
    float*  prodD = (float*)(prodC + PROD_F4);        // [32][40]
    float4* AB    = (float4*)(smem + 66560);          // [24][40]
    float4* Ahs   = (float4*)smem;                    // [24][32] (aliases prodA)

    const int bid = (int)blockIdx.x;                  // 2048
    const int w   = ((bid & 7) << 8) | (bid >> 3);    // XCD slab swizzle
    const int ti  = (w & 31) << 4;                    // row tile
    const int tj  = ((w >> 5) & 15) << 5;             // col tile
    const int n   = w >> 9;
    const int tid = (int)threadIdx.x;

    const size_t plane = (size_t)HH * WW;
    const float* yp = y + (size_t)n * plane;
    const float* xp = x + (size_t)(3 * n) * plane;

    // ---- stage 1: product h-sums, 32 rows x 40 h-cols (320 tasks) ----
    for (int t = tid; t < 320; t += 256) {
        const int r   = t / 10;               // 0..31  (prod row; global gr = ti-8+r)
        const int q   = t % 10;               // 0..9
        const int gr  = ti - 8 + r;
        const int gj0 = tj - 4 + (q << 2);    // h-col base (global)
        const int hc  = q << 2;
        if (gr >= 0 && gr < HH) {
            const bool v0 = (unsigned)(gj0 - 4) <= (unsigned)(WW - 4);
            const bool v1 = (unsigned)(gj0)     <= (unsigned)(WW - 4);
            const bool v2 = (unsigned)(gj0 + 4) <= (unsigned)(WW - 4);
            const float* yr = yp + (size_t)gr * WW;
            const float* ar = xp + (size_t)gr * WW;
            const float* br = ar + plane;
            const float* cr = br + plane;
#define LOADW(Wv, P) { \
            float4 qa = ld4s((P), gj0 - 4, v0); \
            float4 qb = ld4s((P), gj0,     v1); \
            float4 qc = ld4s((P), gj0 + 4, v2); \
            Wv[0]=qa.x; Wv[1]=qa.y; Wv[2]=qa.z;  Wv[3]=qa.w; \
            Wv[4]=qb.x; Wv[5]=qb.y; Wv[6]=qb.z;  Wv[7]=qb.w; \
            Wv[8]=qc.x; Wv[9]=qc.y; Wv[10]=qc.z; Wv[11]=qc.w; }
            float aw[12], bw[12], cw[12], yw[12];
            LOADW(aw, ar); LOADW(bw, br); LOADW(cw, cr); LOADW(yw, yr);
#undef LOADW
            float hs[13][4];
            HBOX(0,  aw[k]);
            HBOX(1,  bw[k]);
            HBOX(2,  cw[k]);
            HBOX(3,  yw[k]);
            HBOX(4,  yw[k] * aw[k]);
            HBOX(5,  yw[k] * bw[k]);
            HBOX(6,  yw[k] * cw[k]);
            HBOX(7,  aw[k] * aw[k]);
            HBOX(8,  aw[k] * bw[k]);
            HBOX(9,  aw[k] * cw[k]);
            HBOX(10, bw[k] * bw[k]);
            HBOX(11, bw[k] * cw[k]);
            HBOX(12, cw[k] * cw[k]);
#pragma unroll
            for (int c = 0; c < 4; ++c) {
                prodA[r * 40 + hc + c] = make_float4(hs[0][c], hs[1][c], hs[2][c],  hs[3][c]);
                prodB[r * 40 + hc + c] = make_float4(hs[4][c], hs[5][c], hs[6][c],  hs[7][c]);
                prodC[r * 40 + hc + c] = make_float4(hs[8][c], hs[9][c], hs[10][c], hs[11][c]);
                prodD[r * 40 + hc + c] = hs[12][c];
            }
        } else {
            const float4 z = make_float4(0.f, 0.f, 0.f, 0.f);
#pragma unroll
            for (int c = 0; c < 4; ++c) {
                prodA[r * 40 + hc + c] = z; prodB[r * 40 + hc + c] = z;
                prodC[r * 40 + hc + c] = z; prodD[r * 40 + hc + c] = 0.f;
            }
        }
    }
    __syncthreads();

    // ---- stage 2a: vertical 9-sum (sliding pair) + solve -> AB[24][40] ----
    for (int t = tid; t < 480; t += 256) {
        const int c  = t % 40;
        const int rp = t / 40;                // 0..11
        const int r0 = rp << 1;               // AB row 0..22; prod window rows r0..r0+9

        float4 fA = prodA[r0 * 40 + c], fB = prodB[r0 * 40 + c], fC = prodC[r0 * 40 + c];
        float  fD = prodD[r0 * 40 + c];
        float4 sA = fA, sB = fB, sC = fC;
        float  sD = fD;
#pragma unroll
        for (int k = 1; k < 9; ++k) {
            sA = f4add(sA, prodA[(r0 + k) * 40 + c]);
            sB = f4add(sB, prodB[(r0 + k) * 40 + c]);
            sC = f4add(sC, prodC[(r0 + k) * 40 + c]);
            sD += prodD[(r0 + k) * 40 + c];
        }

        const int gj = tj - 4 + c;
        const bool cv = (unsigned)gj < (unsigned)WW;
        const int j0r = gj - RR < 0 ? 0 : gj - RR;
        const int j1r = gj + RR > WW - 1 ? WW - 1 : gj + RR;
        const float wcnt = (float)(j1r - j0r + 1);
        const float4 z = make_float4(0.f, 0.f, 0.f, 0.f);

        {
            const int I = ti - 4 + r0;                  // global A,b row
            const bool rv = (unsigned)I < (unsigned)HH;
            const int i0r = I - RR < 0 ? 0 : I - RR;
            const int i1r = I + RR > HH - 1 ? HH - 1 : I + RR;
            const float invn = 1.0f / ((float)(i1r - i0r + 1) * wcnt);
            AB[r0 * 40 + c] = (cv && rv) ? solve_px(sA, sB, sC, sD, invn) : z;
        }
        sA = f4add(f4sub(sA, fA), prodA[(r0 + 9) * 40 + c]);
        sB = f4add(f4sub(sB, fB), prodB[(r0 + 9) * 40 + c]);
        sC = f4add(f4sub(sC, fC), prodC[(r0 + 9) * 40 + c]);
        sD = sD - fD + prodD[(r0 + 9) * 40 + c];
        {
            const int I = ti - 4 + r0 + 1;
            const bool rv = (unsigned)I < (unsigned)HH;
            const int i0r = I - RR < 0 ? 0 : I - RR;
            const int i1r = I + RR > HH - 1 ? HH - 1 : I + RR;
            const float invn = 1.0f / ((float)(i1r - i0r + 1) * wcnt);
            AB[(r0 + 1) * 40 + c] = (cv && rv) ? solve_px(sA, sB, sC, sD, invn) : z;
        }
    }
    __syncthreads();

    // ---- stage 2b: horizontal 9-SUM of AB -> Ahs[24][32] (aliases products) ----
    if (tid < 192) {
        const int r  = tid >> 3;              // 0..23
        const int q  = tid & 7;               // 0..7
        const int lc = q << 2;                // out col local base
        float4 wv[12];
#pragma unroll
        for (int k = 0; k < 12; ++k) wv[k] = AB[r * 40 + lc + k];
        float4 t0 = f4add(f4add(f4add(f4add(wv[0], wv[1]), f4add(wv[2], wv[3])),
                                f4add(f4add(wv[4], wv[5]), f4add(wv[6], wv[7]))), wv[8]);
        float4 t1 = f4add(f4sub(t0, wv[0]), wv[9]);
        float4 t2 = f4add(f4sub(t1, wv[1]), wv[10]);
        float4 t3 = f4add(f4sub(t2, wv[2]), wv[11]);
        Ahs[r * 32 + lc + 0] = t0;
        Ahs[r * 32 + lc + 1] = t1;
        Ahs[r * 32 + lc + 2] = t2;
        Ahs[r * 32 + lc + 3] = t3;
    }
    __syncthreads();

    // ---- stage 3: vertical 9-sum of Ahs (sliding pair) + /N + combine ----
    {
        const int c  = tid & 31;
        const int r0 = (tid >> 5) << 1;       // out rows r0, r0+1 (0..15)

        float4 f0 = Ahs[r0 * 32 + c];
        float4 s  = f0;
#pragma unroll
        for (int k = 1; k < 9; ++k) s = f4add(s, Ahs[(r0 + k) * 32 + c]);

        const int gj  = tj + c;
        const int j0r = gj - RR < 0 ? 0 : gj - RR;
        const int j1r = gj + RR > WW - 1 ? WW - 1 : gj + RR;
        const float jcnt = (float)(j1r - j0r + 1);

        float* op = out + (size_t)n * plane;

#define FIN(S, I) { \
        const int i0r = (I) - RR < 0 ? 0 : (I) - RR; \
        const int i1r = (I) + RR > HH - 1 ? HH - 1 : (I) + RR; \
        const float invn = 1.0f / ((float)(i1r - i0r + 1) * jcnt); \
        const size_t px = (size_t)(I) * WW + gj; \
        const float x0 = xp[px]; \
        const float x1 = xp[px + plane]; \
        const float x2 = xp[px + 2 * plane]; \
        op[px] = (S.x * x0 + S.y * x1 + S.z * x2 + S.w) * invn; }

        FIN(s, ti + r0);
        s = f4add(f4sub(s, f0), Ahs[(r0 + 9) * 32 + c]);
        FIN(s, ti + r0 + 1);
#undef FIN
    }
}

extern "C" void kernel_launch(void* const* d_in, const int* in_sizes, int n_in,
                              void* d_out, int out_size, void* d_ws, size_t ws_size,
                              hipStream_t stream) {
    const float* y = (const float*)d_in[0];   // (4,1,512,512)
    const float* x = (const float*)d_in[1];   // (4,3,512,512)
    float* out = (float*)d_out;               // (4,1,512,512)

    k_all<<<dim3(2048), dim3(256), 0, stream>>>(y, x, out);
}

// Round 9
// 31.367 us; speedup vs baseline: 5.0011x; 1.2970x over previous
//
#include <hip/hip_runtime.h>
#include <hip/hip_fp16.h>

#define HH 512
#define WW 512
#define NB 4
#define RR 4
#define EPSF 1e-8f

// LDS layout (bytes), total 40,960 -> exactly 4 WG/CU (160 KiB):
//   [0,      10240): pA  h4[32][40]   (channels sx0,sx1,sx2,sy)      stages 1-2a
//   [10240,  20480): pB  h4[32][40]   (syx0,syx1,syx2,sxx00)         stages 1-2a
//   [20480,  30720): pC  h4[32][40]   (sxx01,sxx02,sxx11,sxx12)      stages 1-2a
//   [30720,  33280): pD  half[32][40] (sxx22)                        stages 1-2a
//   [33280,  40960): ABh h4[24][40]   (A0,A1,A2,b)                   stages 2a-2b
//   [0,       6144): Ahs h4[24][32]   (aliases pA)                   stages 2b-3
#define SMEM_BYTES 40960

struct __align__(8) h4v { __half2 lo, hi; };

__device__ __forceinline__ h4v pack4(float4 v) {
    h4v r; r.lo = __floats2half2_rn(v.x, v.y); r.hi = __floats2half2_rn(v.z, v.w);
    return r;
}
__device__ __forceinline__ float4 unpack4(h4v p) {
    float2 a = __half22float2(p.lo); float2 b = __half22float2(p.hi);
    return make_float4(a.x, a.y, b.x, b.y);
}
__device__ __forceinline__ float4 f4add(float4 a, float4 b) {
    return make_float4(a.x + b.x, a.y + b.y, a.z + b.z, a.w + b.w);
}
__device__ __forceinline__ float4 f4sub(float4 a, float4 b) {
    return make_float4(a.x - b.x, a.y - b.y, a.z - b.z, a.w - b.w);
}
__device__ __forceinline__ float4 ld4s(const float* p, int off, bool v) {
    const float4 r = *(const float4*)(p + (v ? off : 0));
    return v ? r : make_float4(0.f, 0.f, 0.f, 0.f);
}

// horizontal 9-box of 4 consecutive cols via sliding sums into hs[ch][0..3]
#define HBOX(ch, EXPR) { \
    float p[12]; \
    _Pragma("unroll") for (int k = 0; k < 12; ++k) p[k] = (EXPR); \
    hs[ch][0] = ((p[0]+p[1])+(p[2]+p[3])) + ((p[4]+p[5])+(p[6]+p[7])) + p[8]; \
    hs[ch][1] = hs[ch][0] - p[0] + p[9]; \
    hs[ch][2] = hs[ch][1] - p[1] + p[10]; \
    hs[ch][3] = hs[ch][2] - p[2] + p[11]; }

// 3x3 symmetric solve from grouped box sums -> (A0,A1,A2,b)
__device__ __forceinline__ float4 solve_px(float4 sA, float4 sB, float4 sC, float sD,
                                           float invn) {
    float mx0 = sA.x*invn, mx1 = sA.y*invn, mx2 = sA.z*invn, my = sA.w*invn;
    float cy0 = sB.x*invn - my*mx0;
    float cy1 = sB.y*invn - my*mx1;
    float cy2 = sB.z*invn - my*mx2;
    float a00 = sB.w*invn - mx0*mx0 + EPSF;
    float a01 = sC.x*invn - mx0*mx1;
    float a02 = sC.y*invn - mx0*mx2;
    float a11 = sC.z*invn - mx1*mx1 + EPSF;
    float a12 = sC.w*invn - mx1*mx2;
    float a22 = sD  *invn - mx2*mx2 + EPSF;
    float c00 = a11*a22 - a12*a12;
    float c01 = a02*a12 - a01*a22;
    float c02 = a01*a12 - a02*a11;
    float det = a00*c00 + a01*c01 + a02*c02;
    float id  = 1.0f / det;
    float i00 = c00*id, i01 = c01*id, i02 = c02*id;
    float i11 = (a00*a22 - a02*a02)*id;
    float i12 = (a01*a02 - a00*a12)*id;
    float i22 = (a00*a11 - a01*a01)*id;
    float A0 = cy0*i00 + cy1*i01 + cy2*i02;
    float A1 = cy0*i01 + cy1*i11 + cy2*i12;
    float A2 = cy0*i02 + cy1*i12 + cy2*i22;
    float bb = my - (A0*mx0 + A1*mx1 + A2*mx2);
    return make_float4(A0, A1, A2, bb);
}

// ==================== fully-fused kernel: y,x -> out ====================
// Block owns a 32x16 output tile; all intermediates in fp16-packed LDS.
__global__ __launch_bounds__(256, 4) void k_all(const float* __restrict__ y,
                                                const float* __restrict__ x,
                                                float* __restrict__ out) {
    __shared__ __align__(16) char smem[SMEM_BYTES];
    h4v*    pA  = (h4v*)smem;                   // [32][40]
    h4v*    pB  = pA + 1280;
    h4v*    pC  = pB + 1280;
    __half* pD  = (__half*)(smem + 30720);      // [32][40]
    h4v*    ABh = (h4v*)(smem + 33280);         // [24][40]
    h4v*    Ahs = (h4v*)smem;                   // [24][32] (aliases pA)

    const int bid = (int)blockIdx.x;            // 2048
    const int w   = ((bid & 7) << 8) | (bid >> 3);   // XCD slab swizzle
    const int ti  = (w & 31) << 4;              // row tile
    const int tj  = ((w >> 5) & 15) << 5;       // col tile
    const int n   = w >> 9;
    const int tid = (int)threadIdx.x;

    const size_t plane = (size_t)HH * WW;
    const float* yp = y + (size_t)n * plane;
    const float* xp = x + (size_t)(3 * n) * plane;

    // ---- stage 1: product h-sums, 32 rows x 40 h-cols (320 tasks) ----
    for (int t = tid; t < 320; t += 256) {
        const int r   = t / 10;                 // 0..31 (gr = ti-8+r)
        const int q   = t % 10;                 // 0..9
        const int gr  = ti - 8 + r;
        const int gj0 = tj - 4 + (q << 2);
        const int hc  = q << 2;
        if (gr >= 0 && gr < HH) {
            const bool v0 = (unsigned)(gj0 - 4) <= (unsigned)(WW - 4);
            const bool v1 = (unsigned)(gj0)     <= (unsigned)(WW - 4);
            const bool v2 = (unsigned)(gj0 + 4) <= (unsigned)(WW - 4);
            const float* yr = yp + (size_t)gr * WW;
            const float* ar = xp + (size_t)gr * WW;
            const float* br = ar + plane;
            const float* cr = br + plane;
#define LOADW(Wv, P) { \
            float4 qa = ld4s((P), gj0 - 4, v0); \
            float4 qb = ld4s((P), gj0,     v1); \
            float4 qc = ld4s((P), gj0 + 4, v2); \
            Wv[0]=qa.x; Wv[1]=qa.y; Wv[2]=qa.z;  Wv[3]=qa.w; \
            Wv[4]=qb.x; Wv[5]=qb.y; Wv[6]=qb.z;  Wv[7]=qb.w; \
            Wv[8]=qc.x; Wv[9]=qc.y; Wv[10]=qc.z; Wv[11]=qc.w; }
            float aw[12], bw[12], cw[12], yw[12];
            LOADW(aw, ar); LOADW(bw, br); LOADW(cw, cr); LOADW(yw, yr);
#undef LOADW
            float hs[13][4];
            HBOX(0,  aw[k]);
            HBOX(1,  bw[k]);
            HBOX(2,  cw[k]);
            HBOX(3,  yw[k]);
            HBOX(4,  yw[k] * aw[k]);
            HBOX(5,  yw[k] * bw[k]);
            HBOX(6,  yw[k] * cw[k]);
            HBOX(7,  aw[k] * aw[k]);
            HBOX(8,  aw[k] * bw[k]);
            HBOX(9,  aw[k] * cw[k]);
            HBOX(10, bw[k] * bw[k]);
            HBOX(11, bw[k] * cw[k]);
            HBOX(12, cw[k] * cw[k]);
#pragma unroll
            for (int c = 0; c < 4; ++c) {
                pA[r * 40 + hc + c] = pack4(make_float4(hs[0][c], hs[1][c], hs[2][c],  hs[3][c]));
                pB[r * 40 + hc + c] = pack4(make_float4(hs[4][c], hs[5][c], hs[6][c],  hs[7][c]));
                pC[r * 40 + hc + c] = pack4(make_float4(hs[8][c], hs[9][c], hs[10][c], hs[11][c]));
                pD[r * 40 + hc + c] = __float2half(hs[12][c]);
            }
        } else {
            const h4v z = pack4(make_float4(0.f, 0.f, 0.f, 0.f));
#pragma unroll
            for (int c = 0; c < 4; ++c) {
                pA[r * 40 + hc + c] = z; pB[r * 40 + hc + c] = z;
                pC[r * 40 + hc + c] = z; pD[r * 40 + hc + c] = __float2half(0.f);
            }
        }
    }
    __syncthreads();

    // ---- stage 2a: vertical 9-sum (f32, sliding pair) + solve -> ABh[24][40] ----
    for (int t = tid; t < 480; t += 256) {
        const int c  = t % 40;
        const int rp = t / 40;                  // 0..11
        const int r0 = rp << 1;

        float4 fA = unpack4(pA[r0 * 40 + c]);
        float4 fB = unpack4(pB[r0 * 40 + c]);
        float4 fC = unpack4(pC[r0 * 40 + c]);
        float  fD = __half2float(pD[r0 * 40 + c]);
        float4 sA = fA, sB = fB, sC = fC;
        float  sD = fD;
#pragma unroll
        for (int k = 1; k < 9; ++k) {
            sA = f4add(sA, unpack4(pA[(r0 + k) * 40 + c]));
            sB = f4add(sB, unpack4(pB[(r0 + k) * 40 + c]));
            sC = f4add(sC, unpack4(pC[(r0 + k) * 40 + c]));
            sD += __half2float(pD[(r0 + k) * 40 + c]);
        }

        const int gj = tj - 4 + c;
        const bool cv = (unsigned)gj < (unsigned)WW;
        const int j0r = gj - RR < 0 ? 0 : gj - RR;
        const int j1r = gj + RR > WW - 1 ? WW - 1 : gj + RR;
        const float wcnt = (float)(j1r - j0r + 1);
        const float4 z4 = make_float4(0.f, 0.f, 0.f, 0.f);

        {
            const int I = ti - 4 + r0;
            const bool rv = (unsigned)I < (unsigned)HH;
            const int i0r = I - RR < 0 ? 0 : I - RR;
            const int i1r = I + RR > HH - 1 ? HH - 1 : I + RR;
            const float invn = 1.0f / ((float)(i1r - i0r + 1) * wcnt);
            ABh[r0 * 40 + c] = pack4((cv && rv) ? solve_px(sA, sB, sC, sD, invn) : z4);
        }
        sA = f4add(f4sub(sA, fA), unpack4(pA[(r0 + 9) * 40 + c]));
        sB = f4add(f4sub(sB, fB), unpack4(pB[(r0 + 9) * 40 + c]));
        sC = f4add(f4sub(sC, fC), unpack4(pC[(r0 + 9) * 40 + c]));
        sD = sD - fD + __half2float(pD[(r0 + 9) * 40 + c]);
        {
            const int I = ti - 4 + r0 + 1;
            const bool rv = (unsigned)I < (unsigned)HH;
            const int i0r = I - RR < 0 ? 0 : I - RR;
            const int i1r = I + RR > HH - 1 ? HH - 1 : I + RR;
            const float invn = 1.0f / ((float)(i1r - i0r + 1) * wcnt);
            ABh[(r0 + 1) * 40 + c] = pack4((cv && rv) ? solve_px(sA, sB, sC, sD, invn) : z4);
        }
    }
    __syncthreads();

    // ---- stage 2b: horizontal 9-SUM of ABh -> Ahs[24][32] (aliases products) ----
    if (tid < 192) {
        const int r  = tid >> 3;                // 0..23
        const int q  = tid & 7;                 // 0..7
        const int lc = q << 2;
        float4 wv[12];
#pragma unroll
        for (int k = 0; k < 12; ++k) wv[k] = unpack4(ABh[r * 40 + lc + k]);
        float4 t0 = f4add(f4add(f4add(f4add(wv[0], wv[1]), f4add(wv[2], wv[3])),
                                f4add(f4add(wv[4], wv[5]), f4add(wv[6], wv[7]))), wv[8]);
        float4 t1 = f4add(f4sub(t0, wv[0]), wv[9]);
        float4 t2 = f4add(f4sub(t1, wv[1]), wv[10]);
        float4 t3 = f4add(f4sub(t2, wv[2]), wv[11]);
        Ahs[r * 32 + lc + 0] = pack4(t0);
        Ahs[r * 32 + lc + 1] = pack4(t1);
        Ahs[r * 32 + lc + 2] = pack4(t2);
        Ahs[r * 32 + lc + 3] = pack4(t3);
    }
    __syncthreads();

    // ---- stage 3: vertical 9-sum of Ahs (f32, sliding pair) + /N + combine ----
    {
        const int c  = tid & 31;
        const int r0 = (tid >> 5) << 1;         // out rows r0, r0+1

        float4 f0 = unpack4(Ahs[r0 * 32 + c]);
        float4 s  = f0;
#pragma unroll
        for (int k = 1; k < 9; ++k) s = f4add(s, unpack4(Ahs[(r0 + k) * 32 + c]));

        const int gj  = tj + c;
        const int j0r = gj - RR < 0 ? 0 : gj - RR;
        const int j1r = gj + RR > WW - 1 ? WW - 1 : gj + RR;
        const float jcnt = (float)(j1r - j0r + 1);

        float* op = out + (size_t)n * plane;

#define FIN(S, I) { \
        const int i0r = (I) - RR < 0 ? 0 : (I) - RR; \
        const int i1r = (I) + RR > HH - 1 ? HH - 1 : (I) + RR; \
        const float invn = 1.0f / ((float)(i1r - i0r + 1) * jcnt); \
        const size_t px = (size_t)(I) * WW + gj; \
        const float x0 = xp[px]; \
        const float x1 = xp[px + plane]; \
        const float x2 = xp[px + 2 * plane]; \
        op[px] = (S.x * x0 + S.y * x1 + S.z * x2 + S.w) * invn; }

        FIN(s, ti + r0);
        s = f4add(f4sub(s, f0), unpack4(Ahs[(r0 + 9) * 32 + c]));
        FIN(s, ti + r0 + 1);
#undef FIN
    }
}

extern "C" void kernel_launch(void* const* d_in, const int* in_sizes, int n_in,
                              void* d_out, int out_size, void* d_ws, size_t ws_size,
                              hipStream_t stream) {
    const float* y = (const float*)d_in[0];   // (4,1,512,512)
    const float* x = (const float*)d_in[1];   // (4,3,512,512)
    float* out = (float*)d_out;               // (4,1,512,512)

    k_all<<<dim3(2048), dim3(256), 0, stream>>>(y, x, out);
}

// Round 10
// 26.617 us; speedup vs baseline: 5.8936x; 1.1785x over previous
//
#include <hip/hip_runtime.h>
#include <hip/hip_fp16.h>

#define HH 512
#define WW 512
#define NB 4
#define RR 4
#define EPSF 1e-8f

// Block: 512 threads, 32x32 output tile. LDS (bytes, total 77,408 -> 2 WG/CU):
//   [0,     15744): pA  h4[48][41]   (sx0,sx1,sx2,sy)        stages 1-2a
//   [15744, 31488): pB  h4[48][41]   (syx0,syx1,syx2,sxx00)  stages 1-2a
//   [31488, 47232): pC  h4[48][41]   (sxx01,sxx02,sxx11,sxx12)
//   [47232, 51168): pD  half[48][41] (sxx22)                 stages 1-2a
//   [51168, 77408): ABf float4[40][41] (A0,A1,A2,b)          stages 2a-2b
//   [0,     21120): Ahs float4[40][33] (aliases pA)          stages 2b-3
#define SMEM_BYTES 77408
#define PST 41
#define AST 33

struct __align__(8) h4v { __half2 lo, hi; };

__device__ __forceinline__ h4v pack4(float4 v) {
    h4v r; r.lo = __floats2half2_rn(v.x, v.y); r.hi = __floats2half2_rn(v.z, v.w);
    return r;
}
__device__ __forceinline__ float4 unpack4(h4v p) {
    float2 a = __half22float2(p.lo); float2 b = __half22float2(p.hi);
    return make_float4(a.x, a.y, b.x, b.y);
}
__device__ __forceinline__ float4 f4add(float4 a, float4 b) {
    return make_float4(a.x + b.x, a.y + b.y, a.z + b.z, a.w + b.w);
}
__device__ __forceinline__ float4 f4sub(float4 a, float4 b) {
    return make_float4(a.x - b.x, a.y - b.y, a.z - b.z, a.w - b.w);
}
__device__ __forceinline__ float4 ld4s(const float* p, int off, bool v) {
    const float4 r = *(const float4*)(p + (v ? off : 0));
    return v ? r : make_float4(0.f, 0.f, 0.f, 0.f);
}

#define HBOX(ch, EXPR) { \
    float p[12]; \
    _Pragma("unroll") for (int k = 0; k < 12; ++k) p[k] = (EXPR); \
    hs[ch][0] = ((p[0]+p[1])+(p[2]+p[3])) + ((p[4]+p[5])+(p[6]+p[7])) + p[8]; \
    hs[ch][1] = hs[ch][0] - p[0] + p[9]; \
    hs[ch][2] = hs[ch][1] - p[1] + p[10]; \
    hs[ch][3] = hs[ch][2] - p[2] + p[11]; }

// 3x3 symmetric solve from grouped box sums -> (A0,A1,A2,b)
__device__ __forceinline__ float4 solve_px(float4 sA, float4 sB, float4 sC, float sD,
                                           float invn) {
    float mx0 = sA.x*invn, mx1 = sA.y*invn, mx2 = sA.z*invn, my = sA.w*invn;
    float cy0 = sB.x*invn - my*mx0;
    float cy1 = sB.y*invn - my*mx1;
    float cy2 = sB.z*invn - my*mx2;
    float a00 = sB.w*invn - mx0*mx0 + EPSF;
    float a01 = sC.x*invn - mx0*mx1;
    float a02 = sC.y*invn - mx0*mx2;
    float a11 = sC.z*invn - mx1*mx1 + EPSF;
    float a12 = sC.w*invn - mx1*mx2;
    float a22 = sD  *invn - mx2*mx2 + EPSF;
    float c00 = a11*a22 - a12*a12;
    float c01 = a02*a12 - a01*a22;
    float c02 = a01*a12 - a02*a11;
    float det = a00*c00 + a01*c01 + a02*c02;
    float id  = 1.0f / det;
    float i00 = c00*id, i01 = c01*id, i02 = c02*id;
    float i11 = (a00*a22 - a02*a02)*id;
    float i12 = (a01*a02 - a00*a12)*id;
    float i22 = (a00*a11 - a01*a01)*id;
    float A0 = cy0*i00 + cy1*i01 + cy2*i02;
    float A1 = cy0*i01 + cy1*i11 + cy2*i12;
    float A2 = cy0*i02 + cy1*i12 + cy2*i22;
    float bb = my - (A0*mx0 + A1*mx1 + A2*mx2);
    return make_float4(A0, A1, A2, bb);
}

// ==================== fully-fused kernel: y,x -> out ====================
__global__ __launch_bounds__(512, 4) void k_all(const float* __restrict__ y,
                                                const float* __restrict__ x,
                                                float* __restrict__ out) {
    __shared__ __align__(16) char smem[SMEM_BYTES];
    h4v*    pA  = (h4v*)smem;                   // [48][41]
    h4v*    pB  = pA + 48 * PST;
    h4v*    pC  = pB + 48 * PST;
    __half* pD  = (__half*)(smem + 47232);      // [48][41]
    float4* ABf = (float4*)(smem + 51168);      // [40][41]
    float4* Ahs = (float4*)smem;                // [40][33] (aliases pA)

    const int bid = (int)blockIdx.x;            // 1024
    const int w   = ((bid & 7) << 7) | (bid >> 3);   // XCD slab swizzle
    const int rem = w & 255;
    const int ti  = (rem & 15) << 5;            // row tile
    const int tj  = (rem >> 4) << 5;            // col tile
    const int n   = w >> 8;
    const int tid = (int)threadIdx.x;

    const size_t plane = (size_t)HH * WW;
    const float* yp = y + (size_t)n * plane;
    const float* xp = x + (size_t)(3 * n) * plane;

    // ---- stage 1: product h-sums, 48 rows x 40 h-cols (480 tasks, 1/thread) ----
    if (tid < 480) {
        const int r   = tid / 10;               // 0..47 (gr = ti-8+r)
        const int q   = tid % 10;               // 0..9
        const int gr  = ti - 8 + r;
        const int gj0 = tj - 4 + (q << 2);
        const int hc  = q << 2;
        if (gr >= 0 && gr < HH) {
            const bool v0 = (unsigned)(gj0 - 4) <= (unsigned)(WW - 4);
            const bool v1 = (unsigned)(gj0)     <= (unsigned)(WW - 4);
            const bool v2 = (unsigned)(gj0 + 4) <= (unsigned)(WW - 4);
            const float* yr = yp + (size_t)gr * WW;
            const float* ar = xp + (size_t)gr * WW;
            const float* br = ar + plane;
            const float* cr = br + plane;
#define LOADW(Wv, P) { \
            float4 qa = ld4s((P), gj0 - 4, v0); \
            float4 qb = ld4s((P), gj0,     v1); \
            float4 qc = ld4s((P), gj0 + 4, v2); \
            Wv[0]=qa.x; Wv[1]=qa.y; Wv[2]=qa.z;  Wv[3]=qa.w; \
            Wv[4]=qb.x; Wv[5]=qb.y; Wv[6]=qb.z;  Wv[7]=qb.w; \
            Wv[8]=qc.x; Wv[9]=qc.y; Wv[10]=qc.z; Wv[11]=qc.w; }
            float aw[12], bw[12], cw[12], yw[12];
            LOADW(aw, ar); LOADW(bw, br); LOADW(cw, cr); LOADW(yw, yr);
#undef LOADW
            float hs[13][4];
            HBOX(0,  aw[k]);
            HBOX(1,  bw[k]);
            HBOX(2,  cw[k]);
            HBOX(3,  yw[k]);
            HBOX(4,  yw[k] * aw[k]);
            HBOX(5,  yw[k] * bw[k]);
            HBOX(6,  yw[k] * cw[k]);
            HBOX(7,  aw[k] * aw[k]);
            HBOX(8,  aw[k] * bw[k]);
            HBOX(9,  aw[k] * cw[k]);
            HBOX(10, bw[k] * bw[k]);
            HBOX(11, bw[k] * cw[k]);
            HBOX(12, cw[k] * cw[k]);
#pragma unroll
            for (int c = 0; c < 4; ++c) {
                pA[r * PST + hc + c] = pack4(make_float4(hs[0][c], hs[1][c], hs[2][c],  hs[3][c]));
                pB[r * PST + hc + c] = pack4(make_float4(hs[4][c], hs[5][c], hs[6][c],  hs[7][c]));
                pC[r * PST + hc + c] = pack4(make_float4(hs[8][c], hs[9][c], hs[10][c], hs[11][c]));
                pD[r * PST + hc + c] = __float2half(hs[12][c]);
            }
        } else {
            const h4v z = pack4(make_float4(0.f, 0.f, 0.f, 0.f));
#pragma unroll
            for (int c = 0; c < 4; ++c) {
                pA[r * PST + hc + c] = z; pB[r * PST + hc + c] = z;
                pC[r * PST + hc + c] = z; pD[r * PST + hc + c] = __float2half(0.f);
            }
        }
    }
    __syncthreads();

    // ---- stage 2a: vertical 9-sum (f32, sliding quad) + solve -> ABf[40][41] ----
    if (tid < 400) {
        const int c   = tid % 40;
        const int rp  = tid / 40;               // 0..9
        const int rab = rp << 2;                // AB rows rab..rab+3; window rows rab..rab+11

        float4 sA = make_float4(0.f,0.f,0.f,0.f), sB = sA, sC = sA;
        float  sD = 0.f;
#define ACCP(RI) { const int o = (RI) * PST + c; \
        sA = f4add(sA, unpack4(pA[o])); sB = f4add(sB, unpack4(pB[o])); \
        sC = f4add(sC, unpack4(pC[o])); sD += __half2float(pD[o]); }
#define SUBP(RI) { const int o = (RI) * PST + c; \
        sA = f4sub(sA, unpack4(pA[o])); sB = f4sub(sB, unpack4(pB[o])); \
        sC = f4sub(sC, unpack4(pC[o])); sD -= __half2float(pD[o]); }
#pragma unroll
        for (int k = 0; k < 9; ++k) ACCP(rab + k)

        const int gj = tj - 4 + c;
        const bool cv = (unsigned)gj < (unsigned)WW;
        const int j0r = gj - RR < 0 ? 0 : gj - RR;
        const int j1r = gj + RR > WW - 1 ? WW - 1 : gj + RR;
        const float wcnt = (float)(j1r - j0r + 1);
        const float4 z4 = make_float4(0.f, 0.f, 0.f, 0.f);

#define SOLV(RO) { \
        const int I = ti - 4 + (RO); \
        const bool rv = (unsigned)I < (unsigned)HH; \
        const int i0r = I - RR < 0 ? 0 : I - RR; \
        const int i1r = I + RR > HH - 1 ? HH - 1 : I + RR; \
        const float invn = 1.0f / ((float)(i1r - i0r + 1) * wcnt); \
        ABf[(RO) * PST + c] = (cv && rv) ? solve_px(sA, sB, sC, sD, invn) : z4; }

        SOLV(rab)
        SUBP(rab)      ACCP(rab + 9)
        SOLV(rab + 1)
        SUBP(rab + 1)  ACCP(rab + 10)
        SOLV(rab + 2)
        SUBP(rab + 2)  ACCP(rab + 11)
        SOLV(rab + 3)
#undef SOLV
#undef ACCP
#undef SUBP
    }
    __syncthreads();

    // ---- stage 2b: horizontal 9-SUM of ABf -> Ahs[40][33] (aliases products) ----
    if (tid < 320) {
        const int rab = tid >> 3;               // 0..39
        const int q   = tid & 7;                // 0..7
        const int lc  = q << 2;
        float4 wv[12];
#pragma unroll
        for (int k = 0; k < 12; ++k) wv[k] = ABf[rab * PST + lc + k];
        float4 t0 = f4add(f4add(f4add(f4add(wv[0], wv[1]), f4add(wv[2], wv[3])),
                                f4add(f4add(wv[4], wv[5]), f4add(wv[6], wv[7]))), wv[8]);
        float4 t1 = f4add(f4sub(t0, wv[0]), wv[9]);
        float4 t2 = f4add(f4sub(t1, wv[1]), wv[10]);
        float4 t3 = f4add(f4sub(t2, wv[2]), wv[11]);
        Ahs[rab * AST + lc + 0] = t0;
        Ahs[rab * AST + lc + 1] = t1;
        Ahs[rab * AST + lc + 2] = t2;
        Ahs[rab * AST + lc + 3] = t3;
    }
    __syncthreads();

    // ---- stage 3: vertical 9-sum of Ahs (sliding pair) + /N + combine ----
    {
        const int c3 = tid & 31;
        const int r0 = (tid >> 5) << 1;         // out rows r0, r0+1 (0..31)

        float4 f0 = Ahs[r0 * AST + c3];
        float4 s  = f0;
#pragma unroll
        for (int k = 1; k < 9; ++k) s = f4add(s, Ahs[(r0 + k) * AST + c3]);

        const int gj  = tj + c3;
        const int j0r = gj - RR < 0 ? 0 : gj - RR;
        const int j1r = gj + RR > WW - 1 ? WW - 1 : gj + RR;
        const float jcnt = (float)(j1r - j0r + 1);

        float* op = out + (size_t)n * plane;

#define FIN(S, I) { \
        const int i0r = (I) - RR < 0 ? 0 : (I) - RR; \
        const int i1r = (I) + RR > HH - 1 ? HH - 1 : (I) + RR; \
        const float invn = 1.0f / ((float)(i1r - i0r + 1) * jcnt); \
        const size_t px = (size_t)(I) * WW + gj; \
        const float x0 = xp[px]; \
        const float x1 = xp[px + plane]; \
        const float x2 = xp[px + 2 * plane]; \
        op[px] = (S.x * x0 + S.y * x1 + S.z * x2 + S.w) * invn; }

        FIN(s, ti + r0);
        s = f4add(f4sub(s, f0), Ahs[(r0 + 9) * AST + c3]);
        FIN(s, ti + r0 + 1);
#undef FIN
    }
}

extern "C" void kernel_launch(void* const* d_in, const int* in_sizes, int n_in,
                              void* d_out, int out_size, void* d_ws, size_t ws_size,
                              hipStream_t stream) {
    const float* y = (const float*)d_in[0];   // (4,1,512,512)
    const float* x = (const float*)d_in[1];   // (4,3,512,512)
    float* out = (float*)d_out;               // (4,1,512,512)

    k_all<<<dim3(1024), dim3(512), 0, stream>>>(y, x, out);
}

// Round 11
// 24.261 us; speedup vs baseline: 6.4658x; 1.0971x over previous
//
#include <hip/hip_runtime.h>
#include <hip/hip_fp16.h>

#define HH 512
#define WW 512
#define NB 4
#define RR 4
#define EPSF 1e-8f

// Block: 512 threads, 32x32 output tile. LDS (bytes, total 64,288 -> 2 WG/CU):
//   [0,     15744): pA  h4[48][41]   (sx0,sx1,sx2,sy)        stages 1-2a
//   [15744, 31488): pB  h4[48][41]   (syx0,syx1,syx2,sxx00)  stages 1-2a
//   [31488, 47232): pC  h4[48][41]   (sxx01,sxx02,sxx11,sxx12)
//   [47232, 51168): pD  half[48][41] (sxx22)                 stages 1-2a
//   [51168, 64288): ABh h4[40][41]   (A0,A1,A2,b)            stages 2a-2b
//   [0,     10560): Ahs h4[40][33]   (aliases pA)            stages 2b-3
#define SMEM_BYTES 64288
#define PST 41
#define AST 33

struct __align__(8) h4v { __half2 lo, hi; };

__device__ __forceinline__ h4v pack4(float4 v) {
    h4v r; r.lo = __floats2half2_rn(v.x, v.y); r.hi = __floats2half2_rn(v.z, v.w);
    return r;
}
__device__ __forceinline__ float4 f4add(float4 a, float4 b) {
    return make_float4(a.x + b.x, a.y + b.y, a.z + b.z, a.w + b.w);
}
__device__ __forceinline__ float4 f4sub(float4 a, float4 b) {
    return make_float4(a.x - b.x, a.y - b.y, a.z - b.z, a.w - b.w);
}
__device__ __forceinline__ float4 ld4s(const float* p, int off, bool v) {
    const float4 r = *(const float4*)(p + (v ? off : 0));
    return v ? r : make_float4(0.f, 0.f, 0.f, 0.f);
}

#define HBOX(ch, EXPR) { \
    float p[12]; \
    _Pragma("unroll") for (int k = 0; k < 12; ++k) p[k] = (EXPR); \
    hs[ch][0] = ((p[0]+p[1])+(p[2]+p[3])) + ((p[4]+p[5])+(p[6]+p[7])) + p[8]; \
    hs[ch][1] = hs[ch][0] - p[0] + p[9]; \
    hs[ch][2] = hs[ch][1] - p[1] + p[10]; \
    hs[ch][3] = hs[ch][2] - p[2] + p[11]; }

// 3x3 symmetric solve from grouped box sums -> (A0,A1,A2,b)
__device__ __forceinline__ float4 solve_px(float4 sA, float4 sB, float4 sC, float sD,
                                           float invn) {
    float mx0 = sA.x*invn, mx1 = sA.y*invn, mx2 = sA.z*invn, my = sA.w*invn;
    float cy0 = sB.x*invn - my*mx0;
    float cy1 = sB.y*invn - my*mx1;
    float cy2 = sB.z*invn - my*mx2;
    float a00 = sB.w*invn - mx0*mx0 + EPSF;
    float a01 = sC.x*invn - mx0*mx1;
    float a02 = sC.y*invn - mx0*mx2;
    float a11 = sC.z*invn - mx1*mx1 + EPSF;
    float a12 = sC.w*invn - mx1*mx2;
    float a22 = sD  *invn - mx2*mx2 + EPSF;
    float c00 = a11*a22 - a12*a12;
    float c01 = a02*a12 - a01*a22;
    float c02 = a01*a12 - a02*a11;
    float det = a00*c00 + a01*c01 + a02*c02;
    float id  = 1.0f / det;
    float i00 = c00*id, i01 = c01*id, i02 = c02*id;
    float i11 = (a00*a22 - a02*a02)*id;
    float i12 = (a01*a02 - a00*a12)*id;
    float i22 = (a00*a11 - a01*a01)*id;
    float A0 = cy0*i00 + cy1*i01 + cy2*i02;
    float A1 = cy0*i01 + cy1*i11 + cy2*i12;
    float A2 = cy0*i02 + cy1*i12 + cy2*i22;
    float bb = my - (A0*mx0 + A1*mx1 + A2*mx2);
    return make_float4(A0, A1, A2, bb);
}

// ==================== fully-fused kernel: y,x -> out ====================
__global__ __launch_bounds__(512, 4) void k_all(const float* __restrict__ y,
                                                const float* __restrict__ x,
                                                float* __restrict__ out) {
    __shared__ __align__(16) char smem[SMEM_BYTES];
    h4v*    pA  = (h4v*)smem;                   // [48][41]
    h4v*    pB  = pA + 48 * PST;
    h4v*    pC  = pB + 48 * PST;
    __half* pD  = (__half*)(smem + 47232);      // [48][41]
    h4v*    ABh = (h4v*)(smem + 51168);         // [40][41]
    h4v*    Ahs = (h4v*)smem;                   // [40][33] (aliases pA)

    const int bid = (int)blockIdx.x;            // 1024
    const int w   = ((bid & 7) << 7) | (bid >> 3);   // XCD slab swizzle
    const int rem = w & 255;
    const int ti  = (rem & 15) << 5;            // row tile
    const int tj  = (rem >> 4) << 5;            // col tile
    const int n   = w >> 8;
    const int tid = (int)threadIdx.x;

    const size_t plane = (size_t)HH * WW;
    const float* yp = y + (size_t)n * plane;
    const float* xp = x + (size_t)(3 * n) * plane;

    // ---- stage 1: product h-sums, 48 rows x 40 h-cols (480 tasks, 1/thread) ----
    if (tid < 480) {
        const int r   = tid / 10;               // 0..47 (gr = ti-8+r)
        const int q   = tid % 10;               // 0..9
        const int gr  = ti - 8 + r;
        const int gj0 = tj - 4 + (q << 2);
        const int hc  = q << 2;
        if (gr >= 0 && gr < HH) {
            const bool v0 = (unsigned)(gj0 - 4) <= (unsigned)(WW - 4);
            const bool v1 = (unsigned)(gj0)     <= (unsigned)(WW - 4);
            const bool v2 = (unsigned)(gj0 + 4) <= (unsigned)(WW - 4);
            const float* yr = yp + (size_t)gr * WW;
            const float* ar = xp + (size_t)gr * WW;
            const float* br = ar + plane;
            const float* cr = br + plane;
#define LOADW(Wv, P) { \
            float4 qa = ld4s((P), gj0 - 4, v0); \
            float4 qb = ld4s((P), gj0,     v1); \
            float4 qc = ld4s((P), gj0 + 4, v2); \
            Wv[0]=qa.x; Wv[1]=qa.y; Wv[2]=qa.z;  Wv[3]=qa.w; \
            Wv[4]=qb.x; Wv[5]=qb.y; Wv[6]=qb.z;  Wv[7]=qb.w; \
            Wv[8]=qc.x; Wv[9]=qc.y; Wv[10]=qc.z; Wv[11]=qc.w; }
            float aw[12], bw[12], cw[12], yw[12];
            LOADW(aw, ar); LOADW(bw, br); LOADW(cw, cr); LOADW(yw, yr);
#undef LOADW
            float hs[13][4];
            HBOX(0,  aw[k]);
            HBOX(1,  bw[k]);
            HBOX(2,  cw[k]);
            HBOX(3,  yw[k]);
            HBOX(4,  yw[k] * aw[k]);
            HBOX(5,  yw[k] * bw[k]);
            HBOX(6,  yw[k] * cw[k]);
            HBOX(7,  aw[k] * aw[k]);
            HBOX(8,  aw[k] * bw[k]);
            HBOX(9,  aw[k] * cw[k]);
            HBOX(10, bw[k] * bw[k]);
            HBOX(11, bw[k] * cw[k]);
            HBOX(12, cw[k] * cw[k]);
#pragma unroll
            for (int c = 0; c < 4; ++c) {
                pA[r * PST + hc + c] = pack4(make_float4(hs[0][c], hs[1][c], hs[2][c],  hs[3][c]));
                pB[r * PST + hc + c] = pack4(make_float4(hs[4][c], hs[5][c], hs[6][c],  hs[7][c]));
                pC[r * PST + hc + c] = pack4(make_float4(hs[8][c], hs[9][c], hs[10][c], hs[11][c]));
                pD[r * PST + hc + c] = __float2half(hs[12][c]);
            }
        } else {
            const h4v z = pack4(make_float4(0.f, 0.f, 0.f, 0.f));
#pragma unroll
            for (int c = 0; c < 4; ++c) {
                pA[r * PST + hc + c] = z; pB[r * PST + hc + c] = z;
                pC[r * PST + hc + c] = z; pD[r * PST + hc + c] = __float2half(0.f);
            }
        }
    }
    __syncthreads();

    // ---- stage 2a: packed-fp16 vertical 9-sum (sliding quad) + f32 solve -> ABh ----
    if (tid < 400) {
        const int c   = tid % 40;
        const int rp  = tid / 40;               // 0..9
        const int rab = rp << 2;                // AB rows rab..rab+3

        __half2 a0, a1, b0, b1, c0, c1;
        __half  dd;
        {
            const int o = rab * PST + c;
            a0 = pA[o].lo; a1 = pA[o].hi;
            b0 = pB[o].lo; b1 = pB[o].hi;
            c0 = pC[o].lo; c1 = pC[o].hi;
            dd = pD[o];
        }
#pragma unroll
        for (int k = 1; k < 9; ++k) {
            const int o = (rab + k) * PST + c;
            a0 = __hadd2(a0, pA[o].lo); a1 = __hadd2(a1, pA[o].hi);
            b0 = __hadd2(b0, pB[o].lo); b1 = __hadd2(b1, pB[o].hi);
            c0 = __hadd2(c0, pC[o].lo); c1 = __hadd2(c1, pC[o].hi);
            dd = __hadd(dd, pD[o]);
        }

        const int gj = tj - 4 + c;
        const bool cv = (unsigned)gj < (unsigned)WW;
        const int j0r = gj - RR < 0 ? 0 : gj - RR;
        const int j1r = gj + RR > WW - 1 ? WW - 1 : gj + RR;
        const float wcnt = (float)(j1r - j0r + 1);
        const float4 z4 = make_float4(0.f, 0.f, 0.f, 0.f);

#define SOLVH(RO) { \
        const int I = ti - 4 + (RO); \
        const bool rv = (unsigned)I < (unsigned)HH; \
        const int i0r = I - RR < 0 ? 0 : I - RR; \
        const int i1r = I + RR > HH - 1 ? HH - 1 : I + RR; \
        const float invn = 1.0f / ((float)(i1r - i0r + 1) * wcnt); \
        float2 xa0 = __half22float2(a0), xa1 = __half22float2(a1); \
        float2 xb0 = __half22float2(b0), xb1 = __half22float2(b1); \
        float2 xc0 = __half22float2(c0), xc1 = __half22float2(c1); \
        float  xd  = __half2float(dd); \
        float4 res = solve_px(make_float4(xa0.x, xa0.y, xa1.x, xa1.y), \
                              make_float4(xb0.x, xb0.y, xb1.x, xb1.y), \
                              make_float4(xc0.x, xc0.y, xc1.x, xc1.y), xd, invn); \
        ABh[(RO) * PST + c] = pack4((cv && rv) ? res : z4); }

#define SLID(RO, RN) { \
        const int o1 = (RO) * PST + c, o2 = (RN) * PST + c; \
        a0 = __hadd2(__hsub2(a0, pA[o1].lo), pA[o2].lo); \
        a1 = __hadd2(__hsub2(a1, pA[o1].hi), pA[o2].hi); \
        b0 = __hadd2(__hsub2(b0, pB[o1].lo), pB[o2].lo); \
        b1 = __hadd2(__hsub2(b1, pB[o1].hi), pB[o2].hi); \
        c0 = __hadd2(__hsub2(c0, pC[o1].lo), pC[o2].lo); \
        c1 = __hadd2(__hsub2(c1, pC[o1].hi), pC[o2].hi); \
        dd = __hadd(__hsub(dd, pD[o1]), pD[o2]); }

        SOLVH(rab)
        SLID(rab,     rab + 9)
        SOLVH(rab + 1)
        SLID(rab + 1, rab + 10)
        SOLVH(rab + 2)
        SLID(rab + 2, rab + 11)
        SOLVH(rab + 3)
#undef SOLVH
#undef SLID
    }
    __syncthreads();

    // ---- stage 2b: packed-fp16 horizontal 9-SUM of ABh -> Ahs[40][33] ----
    if (tid < 320) {
        const int rab = tid >> 3;               // 0..39
        const int q   = tid & 7;                // 0..7
        const int lc  = q << 2;
        h4v wv[12];
#pragma unroll
        for (int k = 0; k < 12; ++k) wv[k] = ABh[rab * PST + lc + k];
        __half2 lo = wv[0].lo, hi = wv[0].hi;
#pragma unroll
        for (int k = 1; k < 9; ++k) { lo = __hadd2(lo, wv[k].lo); hi = __hadd2(hi, wv[k].hi); }
        h4v t; t.lo = lo; t.hi = hi;
        Ahs[rab * AST + lc + 0] = t;
#pragma unroll
        for (int s = 0; s < 3; ++s) {
            lo = __hadd2(__hsub2(lo, wv[s].lo), wv[s + 9].lo);
            hi = __hadd2(__hsub2(hi, wv[s].hi), wv[s + 9].hi);
            t.lo = lo; t.hi = hi;
            Ahs[rab * AST + lc + 1 + s] = t;
        }
    }
    __syncthreads();

    // ---- stage 3: packed-fp16 vertical 9-sum of Ahs + /N + combine (f32) ----
    {
        const int c3 = tid & 31;
        const int r0 = (tid >> 5) << 1;         // out rows r0, r0+1 (0..31)

        const h4v f0 = Ahs[r0 * AST + c3];
        __half2 slo = f0.lo, shi = f0.hi;
#pragma unroll
        for (int k = 1; k < 9; ++k) {
            const h4v v = Ahs[(r0 + k) * AST + c3];
            slo = __hadd2(slo, v.lo); shi = __hadd2(shi, v.hi);
        }

        const int gj  = tj + c3;
        const int j0r = gj - RR < 0 ? 0 : gj - RR;
        const int j1r = gj + RR > WW - 1 ? WW - 1 : gj + RR;
        const float jcnt = (float)(j1r - j0r + 1);

        float* op = out + (size_t)n * plane;

#define FIN(I) { \
        const int i0r = (I) - RR < 0 ? 0 : (I) - RR; \
        const int i1r = (I) + RR > HH - 1 ? HH - 1 : (I) + RR; \
        const float invn = 1.0f / ((float)(i1r - i0r + 1) * jcnt); \
        float2 flo = __half22float2(slo), fhi = __half22float2(shi); \
        const size_t px = (size_t)(I) * WW + gj; \
        const float x0 = xp[px]; \
        const float x1 = xp[px + plane]; \
        const float x2 = xp[px + 2 * plane]; \
        op[px] = (flo.x * x0 + flo.y * x1 + fhi.x * x2 + fhi.y) * invn; }

        FIN(ti + r0);
        {
            const h4v v9 = Ahs[(r0 + 9) * AST + c3];
            slo = __hadd2(__hsub2(slo, f0.lo), v9.lo);
            shi = __hadd2(__hsub2(shi, f0.hi), v9.hi);
        }
        FIN(ti + r0 + 1);
#undef FIN
    }
}

extern "C" void kernel_launch(void* const* d_in, const int* in_sizes, int n_in,
                              void* d_out, int out_size, void* d_ws, size_t ws_size,
                              hipStream_t stream) {
    const float* y = (const float*)d_in[0];   // (4,1,512,512)
    const float* x = (const float*)d_in[1];   // (4,3,512,512)
    float* out = (float*)d_out;               // (4,1,512,512)

    k_all<<<dim3(1024), dim3(512), 0, stream>>>(y, x, out);
}